// Round 20
// baseline (112.540 us; speedup 1.0000x reference)
//
#include <hip/hip_runtime.h>
#include <math.h>

using u8  = unsigned char;
using u32 = unsigned int;
using u64 = unsigned long long;

typedef short short8 __attribute__((ext_vector_type(8)));
typedef float f32x4  __attribute__((ext_vector_type(4)));
typedef float f32x2  __attribute__((ext_vector_type(2)));

#define MC 2048
#define NC 2048
#define DF 256
#define NFULL 50000
#define NBACK 30000
#define KCORR 4096
#define MAXPTS 256
#define NN_CHUNK 196   // 256 chunks * 196 = 50176 >= 50000; 49 groups of 4
#define BM_WORDS_I 1568

// ---------------- workspace layout ----------------
constexpr size_t OFF_ROWP = 0;                                // 64*2048 float4 = 2 MB
constexpr size_t OFF_COLP = (size_t)2 * 1024 * 1024;          // 32*2048 float4 = 1 MB
constexpr size_t OFF_GTB  = (size_t)3 * 1024 * 1024;          // 2048*64 u32 = 512 KB (bitfield)
constexpr size_t OFF_NN   = OFF_GTB + (size_t)512 * 1024;     // 4096 u64 = 32 KB
constexpr size_t OFF_CAND = OFF_NN + 4096 * 8;                // 4096 u64 = 32 KB
constexpr size_t OFF_ACC  = OFF_CAND + 4096 * 8;              // 8 f32
constexpr size_t OFF_CNT  = OFF_ACC + 256;                    // counters/tickets
constexpr size_t OFF_BM   = OFF_CNT + 256;                    // 2*1568 u32 = 12.5 KB
constexpr size_t OFF_HASH = OFF_BM + 3200 * 4;                // 8192 u64 = 64 KB

// cnt[] map: 0=cand count, 1=merge ticket, 2=mscA ticket, 3=mscB ticket

__device__ __forceinline__ u32 mask_of(const u64* nn, const u32* bm, int idx, int side) {
    u32 j = (u32)(nn[idx] & 0xFFFFFFFFull);
    return (bm[side * BM_WORDS_I + (j >> 5)] >> (j & 31)) & 1u;
}

__device__ __forceinline__ void circle_terms(float d, bool g, float& lp, float& ln) {
    if (g) { float a = d - 0.1f; lp = a > 0.f ? 24.f*a*a : 0.f; ln = 0.f; }
    else   { float b = 1.4f - d; ln = b > 0.f ? 24.f*b*b : 0.f; lp = 0.f; }
}

__device__ __forceinline__ float softplus_(float x) {
    return fmaxf(x, 0.f) + log1pf(expf(-fabsf(x)));
}

// online-LSE merge: (M,S) <- (M,S) + (M2,S2)
__device__ __forceinline__ void lse_merge(float& M, float& S, float M2, float S2) {
    float nm = fmaxf(M, M2);
    S = S * expf(M - nm) + S2 * expf(M2 - nm);
    M = nm;
}

// block-wide ticket barrier
__device__ __forceinline__ void block_barrier(u32* counter, u32 target, u32* s_tic) {
    __threadfence();
    __syncthreads();
    if (threadIdx.x == 0) {
        *s_tic = atomicAdd(counter, 1u);
        while (__hip_atomic_load(counter, __ATOMIC_ACQUIRE, __HIP_MEMORY_SCOPE_AGENT) < target) {}
    }
    __syncthreads();
}

// ---------------- init: zero gtb/hash/nn/bm/acc/cnt ----------------
__global__ __launch_bounds__(256) void k_init(uint4* __restrict__ gtb4, u64* __restrict__ nn,
                                              float* __restrict__ acc, u64* __restrict__ hash,
                                              u32* __restrict__ cnt, u32* __restrict__ bm) {
    int e = blockIdx.x * 256 + threadIdx.x;   // 0..32767
    gtb4[e] = make_uint4(0u, 0u, 0u, 0u);
    if (e < 8192) hash[e] = 0ull;
    if (e < 4096) nn[e] = ~0ull;
    if (e < 2 * BM_WORDS_I) bm[e] = 0u;
    if (e < 8) acc[e] = 0.f;
    if (e < 8) cnt[e] = 0u;
}

// ---------------- NN argmin: SoA-by-4 LDS, packed-f32, IPT=8 ----------------
// grid: x = 256 chunks, y = side. 512 blocks, 2/CU. One block covers all 2048
// corr points (8 per thread); 4 LDS b128 reads serve 32 evals (R19 lesson:
// k_nn is LDS-throughput-bound at ~0.5 reads/eval; IPT=8 gives 0.125/eval ->
// LDS floor ~8us, VALU floor ~7us). Same pk math + rescan as R13 (proven).
__global__ __launch_bounds__(256) void k_nn(
        const float* __restrict__ fr, const float* __restrict__ fs,
        const float* __restrict__ cr, const float* __restrict__ cs,
        const int* __restrict__ rbi, const int* __restrict__ sbi,
        u32* __restrict__ bm, u64* __restrict__ nn) {
    const int side = blockIdx.y;
    const float* full = side ? fs : fr;
    const float* corr = side ? cs : cr;
    const int ch = blockIdx.x;   // 0..255
    const int t = threadIdx.x;

    // folded k_bm: 235*256 = 60160 >= 60000 entries (side-0 blocks 0..234)
    int gb = side * 256 + ch;
    if (gb < 235) {
        int e = gb * 256 + t;
        if (e < 2 * NBACK) {
            int s2 = e < NBACK ? 0 : 1;
            int v = s2 ? sbi[e - NBACK] : rbi[e];
            atomicOr(&bm[s2 * BM_WORDS_I + (v >> 5)], 1u << (v & 31));
        }
    }

    __shared__ float4 sx4[49], sy4[49], sz4[49], sw4[49];
    const int j0 = ch * NN_CHUNK;
    if (t < 49) {
        int b4 = j0 + t * 4;
        float xx[4], yy[4], zz[4], ww[4];
        #pragma unroll
        for (int u = 0; u < 4; ++u) {
            int j = b4 + u;
            if (j < NFULL) {
                float x = full[j*3], y = full[j*3+1], z = full[j*3+2];
                xx[u] = x; yy[u] = y; zz[u] = z;
                ww[u] = fmaf(x, x, fmaf(y, y, z*z));
            } else {
                xx[u] = 0.f; yy[u] = 0.f; zz[u] = 0.f; ww[u] = 3.0e38f;  // sentinel
            }
        }
        sx4[t] = make_float4(xx[0], xx[1], xx[2], xx[3]);
        sy4[t] = make_float4(yy[0], yy[1], yy[2], yy[3]);
        sz4[t] = make_float4(zz[0], zz[1], zz[2], zz[3]);
        sw4[t] = make_float4(ww[0], ww[1], ww[2], ww[3]);
    }

    float ax[8], ay[8], az[8], bd[8];
    int bg[8];
    #pragma unroll
    for (int q = 0; q < 8; ++q) {
        int i = q * 256 + t;
        float cx = corr[i*3], cy = corr[i*3+1], cz = corr[i*3+2];
        ax[q] = -2.f*cx; ay[q] = -2.f*cy; az[q] = -2.f*cz;
        bd[q] = 3.4e38f; bg[q] = 0;
    }
    __syncthreads();

    for (int g = 0; g < 49; ++g) {
        float4 X = sx4[g], Y = sy4[g], Z = sz4[g], W = sw4[g];
        f32x2 xlo = {X.x, X.y}, xhi = {X.z, X.w};
        f32x2 ylo = {Y.x, Y.y}, yhi = {Y.z, Y.w};
        f32x2 zlo = {Z.x, Z.y}, zhi = {Z.z, Z.w};
        f32x2 wlo = {W.x, W.y}, whi = {W.z, W.w};
        #pragma unroll
        for (int q = 0; q < 8; ++q) {
            f32x2 aq = {ax[q], ax[q]}, bq = {ay[q], ay[q]}, cq2 = {az[q], az[q]};
            f32x2 dlo = __builtin_elementwise_fma(aq, xlo,
                          __builtin_elementwise_fma(bq, ylo,
                            __builtin_elementwise_fma(cq2, zlo, wlo)));
            f32x2 dhi = __builtin_elementwise_fma(aq, xhi,
                          __builtin_elementwise_fma(bq, yhi,
                            __builtin_elementwise_fma(cq2, zhi, whi)));
            f32x2 m2 = __builtin_elementwise_min(dlo, dhi);
            float gm = fminf(m2.x, m2.y);
            bool win = gm < bd[q];
            bd[q] = fminf(bd[q], gm);
            bg[q] = win ? g : bg[q];
        }
    }

    #pragma unroll
    for (int q = 0; q < 8; ++q) {
        // rescan winning group with identical float2 expressions
        int gsel = bg[q];
        float4 X = sx4[gsel], Y = sy4[gsel], Z = sz4[gsel], W = sw4[gsel];
        f32x2 xlo = {X.x, X.y}, xhi = {X.z, X.w};
        f32x2 ylo = {Y.x, Y.y}, yhi = {Y.z, Y.w};
        f32x2 zlo = {Z.x, Z.y}, zhi = {Z.z, Z.w};
        f32x2 wlo = {W.x, W.y}, whi = {W.z, W.w};
        f32x2 aq = {ax[q], ax[q]}, bq = {ay[q], ay[q]}, cq2 = {az[q], az[q]};
        f32x2 dlo = __builtin_elementwise_fma(aq, xlo,
                      __builtin_elementwise_fma(bq, ylo,
                        __builtin_elementwise_fma(cq2, zlo, wlo)));
        f32x2 dhi = __builtin_elementwise_fma(aq, xhi,
                      __builtin_elementwise_fma(bq, yhi,
                        __builtin_elementwise_fma(cq2, zhi, whi)));
        float dv[4] = {dlo.x, dlo.y, dhi.x, dhi.y};
        u32 bj = (u32)(j0 + gsel * 4);
        bool found = false;
        #pragma unroll
        for (int u = 0; u < 4; ++u) {
            if (!found && dv[u] == bd[q]) { bj = (u32)(j0 + gsel*4 + u); found = true; }
        }
        int i = q * 256 + t;
        float cn = 0.25f * fmaf(ax[q], ax[q], fmaf(ay[q], ay[q], az[q]*az[q]));
        float bf = bd[q] + cn;
        u32 db = __float_as_uint(bf);
        db = (db & 0x80000000u) ? ~db : (db | 0x80000000u);
        atomicMin(&nn[side * 2048 + i], ((u64)db << 32) | bj);
    }
}

// ---------------- fused scatter chain: scat1+loss2 | scat2 | top-cap (R15/R19) ----
__global__ __launch_bounds__(256) void k_msc(
        const u64* __restrict__ nn, const u32* __restrict__ bm,
        const float* __restrict__ spm, const int* __restrict__ gti,
        const float* __restrict__ gtv,
        u32* __restrict__ gtb, u64* __restrict__ hash, u64* __restrict__ cand,
        u32* __restrict__ cnt, float* __restrict__ acc) {
    const int b = blockIdx.x, t = threadIdx.x;
    __shared__ u64 keys[4096];
    __shared__ u32 s_tic;

    // ---- phase A: scat1 (blocks 0-15) + loss2 (block 16) ----
    if (b < 16) {
        int k = b * 256 + t;
        int xi = gti[2*k], yi = gti[2*k+1];
        u32 cell = (u32)(xi * 2048 + yi);
        u32 masked = mask_of(nn, bm, xi, 0) & mask_of(nn, bm, 2048 + yi, 1);
        if (masked) atomicOr(&gtb[xi * 64 + (yi >> 5)], 1u << (yi & 31));
        u64 val = ((u64)(cell + 1) << 13) | ((u64)masked << 12) | (u32)k;
        u32 h = (cell * 2654435761u) >> 19;
        while (true) {
            u64 cur = hash[h];
            if (cur == 0ull) cur = atomicCAS(&hash[h], 0ull, val);
            if (cur == 0ull) break;
            if ((cur >> 13) == (u64)(cell + 1)) { atomicMax(&hash[h], val); break; }
            h = (h + 1) & 8191;
        }
    } else if (b == 16) {
        float* red = (float*)keys;
        float c = 0.f;
        for (int e = t; e < 4096; e += 256)
            c += fabsf((1.f - spm[e]) - (float)mask_of(nn, bm, e, e >> 11));
        for (int o = 32; o; o >>= 1) c += __shfl_xor(c, o);
        if ((t & 63) == 0) red[t >> 6] = c;
        __syncthreads();
        if (t == 0) acc[2] = red[0] + red[1] + red[2] + red[3];
    }
    block_barrier(&cnt[2], 32u, &s_tic);

    // ---- phase B: scat2 (all 32 blocks) ----
    {
        int e = b * 256 + t;   // 0..8191
        u64 s = __hip_atomic_load(&hash[e], __ATOMIC_RELAXED, __HIP_MEMORY_SCOPE_AGENT);
        if (s != 0ull && ((s >> 12) & 1ull)) {
            u32 cell = (u32)(s >> 13) - 1u;
            u32 kk = (u32)(s & 0xFFFull);
            u32 vb = __float_as_uint(gtv[kk]);   // overlaps >= 0 -> bits monotonic
            u32 idx = atomicAdd(&cnt[0], 1u);
            cand[idx] = ((u64)vb << 22) | (u32)(0x3FFFFF - cell);
        }
    }
    block_barrier(&cnt[3], 32u, &s_tic);

    // ---- phase C: top-256 cap (blocks 0-15) ----
    if (b < 16) {
        const int n = (int)__hip_atomic_load(&cnt[0], __ATOMIC_RELAXED, __HIP_MEMORY_SCOPE_AGENT);
        if (n > MAXPTS && b * 256 < n) {
            for (int e = t; e < n; e += 256)
                keys[e] = __hip_atomic_load(&cand[e], __ATOMIC_RELAXED, __HIP_MEMORY_SCOPE_AGENT);
            __syncthreads();
            int c = b * 256 + t;
            if (c < n) {
                u64 me = keys[c];
                int rank = 0;
                #pragma unroll 4
                for (int j = 0; j < n; ++j) rank += (keys[j] > me);
                if (rank >= MAXPTS) {
                    u32 cell = 0x3FFFFFu - (u32)(me & 0x3FFFFFull);
                    int row = cell >> 11, col = cell & 2047;
                    atomicAnd(&gtb[row * 64 + (col >> 5)], ~(1u << (col & 31)));
                }
            }
        }
    }
}

// ---------------- fused MFMA bf16 GEMM + laplace + row/col LSE partials (R13) ------
__global__ __launch_bounds__(256) void k_gemm(
        const float* __restrict__ A, const float* __restrict__ B,
        const float* __restrict__ spm, const u32* __restrict__ gtb,
        float4* __restrict__ rowp, float4* __restrict__ colp) {
    __shared__ __align__(16) short As[16384];   // 32 KB
    __shared__ __align__(16) short Bs[8192];    // 16 KB
    __shared__ u32 gtw[256];                    // 1 KB
    const int t = threadIdx.x;
    const int l = t & 63, wid = t >> 6;
    const int wm = wid >> 1, wn = wid & 1;
    const int i0 = blockIdx.y * 128, j0 = blockIdx.x * 64;

    gtw[t] = gtb[(size_t)(i0 + (t >> 1)) * 64 + (j0 >> 5) + (t & 1)];

    f32x4 acc[4][2] = {};

    for (int ks = 0; ks < 2; ++ks) {
        __syncthreads();
        #pragma unroll
        for (int it = 0; it < 12; ++it) {
            int sl = it * 256 + t;                 // 0..3071 slots of 16B
            int c = sl & 63, q = c >> 4, r15 = c & 15;
            const float* src;
            short* dst;
            int kf;
            if (it < 8) {                          // A: slots 0..2047
                int frag = sl >> 6;                // mf(8) x kf(4)
                kf = frag & 3;
                int row = (frag >> 2) * 16 + r15;
                src = A + (size_t)(i0 + row) * 256;
                dst = &As[sl * 8];
            } else {                               // B: slots 2048..3071
                int sl2 = sl - 2048;
                int frag = sl2 >> 6;               // nf(4) x kf(4)
                kf = frag & 3;
                int row = (frag >> 2) * 16 + r15;
                src = B + (size_t)(j0 + row) * 256;
                dst = &Bs[sl2 * 8];
            }
            int col = ks * 128 + kf * 32 + q * 8;
            float4 v0 = *(const float4*)(src + col);
            float4 v1 = *(const float4*)(src + col + 4);
            u32 w0 = __builtin_amdgcn_perm(__float_as_uint(v0.y), __float_as_uint(v0.x), 0x07060302u);
            u32 w1 = __builtin_amdgcn_perm(__float_as_uint(v0.w), __float_as_uint(v0.z), 0x07060302u);
            u32 w2 = __builtin_amdgcn_perm(__float_as_uint(v1.y), __float_as_uint(v1.x), 0x07060302u);
            u32 w3 = __builtin_amdgcn_perm(__float_as_uint(v1.w), __float_as_uint(v1.z), 0x07060302u);
            *(uint4*)dst = make_uint4(w0, w1, w2, w3);
        }
        __syncthreads();

        #pragma unroll
        for (int kf = 0; kf < 4; ++kf) {
            short8 a[4], b[2];
            #pragma unroll
            for (int mi = 0; mi < 4; ++mi)
                a[mi] = *(const short8*)&As[(((wm*4 + mi)*4 + kf) << 9) + l*8];
            #pragma unroll
            for (int ni = 0; ni < 2; ++ni)
                b[ni] = *(const short8*)&Bs[(((wn*2 + ni)*4 + kf) << 9) + l*8];
            #pragma unroll
            for (int mi = 0; mi < 4; ++mi)
                #pragma unroll
                for (int ni = 0; ni < 2; ++ni)
                    acc[mi][ni] = __builtin_amdgcn_mfma_f32_16x16x32_bf16(
                        a[mi], b[ni], acc[mi][ni], 0, 0, 0);
        }
    }

    // epilogue: C/D layout col=lane&15, row=(lane>>4)*4+reg [m89-verified]
    const int cq = l >> 4, cr = l & 15;
    const int rows0 = i0 + wm * 64, cols0 = j0 + wn * 32;

    float vmj[2];
    #pragma unroll
    for (int ni = 0; ni < 2; ++ni) vmj[ni] = 1.f - spm[2048 + cols0 + ni*16 + cr];
    float vmi[4][4];
    #pragma unroll
    for (int mi = 0; mi < 4; ++mi)
        #pragma unroll
        for (int rr = 0; rr < 4; ++rr)
            vmi[mi][rr] = 1.f - spm[rows0 + mi*16 + cq*4 + rr];

    u32 gmask = 0;
    #pragma unroll
    for (int mi = 0; mi < 4; ++mi)
        #pragma unroll
        for (int rr = 0; rr < 4; ++rr) {
            u32 w = gtw[(wm*64 + mi*16 + cq*4 + rr) * 2 + wn];
            #pragma unroll
            for (int ni = 0; ni < 2; ++ni)
                if ((w >> (ni*16 + cr)) & 1u) gmask |= 1u << (mi*8 + ni*4 + rr);
        }
    #pragma unroll
    for (int mi = 0; mi < 4; ++mi)
        #pragma unroll
        for (int ni = 0; ni < 2; ++ni)
            #pragma unroll
            for (int rr = 0; rr < 4; ++rr) {
                float s  = acc[mi][ni][rr];
                float fs = fmaxf(2.f - 2.f*s, 0.f);
                acc[mi][ni][rr] = sqrtf(fs) * expf(0.5f * vmi[mi][rr] * vmj[ni]);
            }

    const int jt2 = blockIdx.x * 2 + wn;   // 0..63
    const int it2 = blockIdx.y * 2 + wm;   // 0..31

    #pragma unroll
    for (int mi = 0; mi < 4; ++mi)
        #pragma unroll
        for (int rr = 0; rr < 4; ++rr) {
            float lp0, ln0, lp1, ln1;
            circle_terms(acc[mi][0][rr], (gmask >> (mi*8 + rr)) & 1, lp0, ln0);
            circle_terms(acc[mi][1][rr], (gmask >> (mi*8 + 4 + rr)) & 1, lp1, ln1);
            float mp = fmaxf(lp0, lp1), mn = fmaxf(ln0, ln1);
            #pragma unroll
            for (int o = 1; o < 16; o <<= 1) {
                mp = fmaxf(mp, __shfl_xor(mp, o));
                mn = fmaxf(mn, __shfl_xor(mn, o));
            }
            float sp = expf(lp0 - mp) + expf(lp1 - mp);
            float sn = expf(ln0 - mn) + expf(ln1 - mn);
            #pragma unroll
            for (int o = 1; o < 16; o <<= 1) {
                sp += __shfl_xor(sp, o);
                sn += __shfl_xor(sn, o);
            }
            if (cr == mi*4 + rr) {
                int row = rows0 + mi*16 + cq*4 + rr;
                rowp[(size_t)jt2 * 2048 + row] = make_float4(mp, sp, mn, sn);
            }
        }

    #pragma unroll
    for (int ni = 0; ni < 2; ++ni) {
        float lp[16], ln[16];
        #pragma unroll
        for (int mi = 0; mi < 4; ++mi)
            #pragma unroll
            for (int rr = 0; rr < 4; ++rr)
                circle_terms(acc[mi][ni][rr], (gmask >> (mi*8 + ni*4 + rr)) & 1,
                             lp[mi*4+rr], ln[mi*4+rr]);
        float mp = lp[0], mn = ln[0];
        #pragma unroll
        for (int e = 1; e < 16; ++e) { mp = fmaxf(mp, lp[e]); mn = fmaxf(mn, ln[e]); }
        #pragma unroll
        for (int o = 16; o < 64; o <<= 1) {
            mp = fmaxf(mp, __shfl_xor(mp, o));
            mn = fmaxf(mn, __shfl_xor(mn, o));
        }
        float sp = 0.f, sn = 0.f;
        #pragma unroll
        for (int e = 0; e < 16; ++e) { sp += expf(lp[e] - mp); sn += expf(ln[e] - mn); }
        #pragma unroll
        for (int o = 16; o < 64; o <<= 1) {
            sp += __shfl_xor(sp, o);
            sn += __shfl_xor(sn, o);
        }
        if (cq == 0) {
            int col = cols0 + ni*16 + cr;
            colp[(size_t)it2 * 2048 + col] = make_float4(mp, sp, mn, sn);
        }
    }
}

// ---------------- merge partials: 64 blocks, 4 threads/element (R18, proven) ------
__global__ __launch_bounds__(256) void k_merge(const float4* __restrict__ rowp,
                                               const float4* __restrict__ colp,
                                               float* __restrict__ acc,
                                               u32* __restrict__ cnt,
                                               float* __restrict__ out) {
    const int t = threadIdx.x;
    const int b = blockIdx.x;    // 0..63
    const int sub = t & 3;
    float Mp = -1e30f, Sp = 0.f, Mn = -1e30f, Sn = 0.f;

    if (b < 32) {
        int row = (b * 256 + t) >> 2;           // 0..2047
        int base = sub * 16;
        #pragma unroll
        for (int j = 0; j < 16; j += 8) {
            float4 pb[8];
            #pragma unroll
            for (int u = 0; u < 8; ++u)
                pb[u] = rowp[(size_t)(base + j + u) * 2048 + row];
            #pragma unroll
            for (int u = 0; u < 8; ++u) {
                lse_merge(Mp, Sp, pb[u].x, pb[u].y);
                lse_merge(Mn, Sn, pb[u].z, pb[u].w);
            }
        }
    } else {
        int col = ((b - 32) * 256 + t) >> 2;    // 0..2047
        int base = sub * 8;
        float4 pb[8];
        #pragma unroll
        for (int u = 0; u < 8; ++u)
            pb[u] = colp[(size_t)(base + u) * 2048 + col];
        #pragma unroll
        for (int u = 0; u < 8; ++u) {
            lse_merge(Mp, Sp, pb[u].x, pb[u].y);
            lse_merge(Mn, Sn, pb[u].z, pb[u].w);
        }
    }

    #pragma unroll
    for (int o = 1; o < 4; o <<= 1) {
        float M2 = __shfl_xor(Mp, o), S2 = __shfl_xor(Sp, o);
        lse_merge(Mp, Sp, M2, S2);
        M2 = __shfl_xor(Mn, o); S2 = __shfl_xor(Sn, o);
        lse_merge(Mn, Sn, M2, S2);
    }

    float lv = 0.f;
    if (sub == 0) {
        float x = (Mp + logf(Sp)) + (Mn + logf(Sn));
        lv = softplus_(x) * (1.f / 24.f);
    }
    for (int o = 32; o; o >>= 1) lv += __shfl_xor(lv, o);
    __shared__ float wsum[4];
    __shared__ u32 tic;
    if ((t & 63) == 0) wsum[t >> 6] = lv;
    __syncthreads();
    if (t == 0) {
        atomicAdd(&acc[b < 32 ? 0 : 1], wsum[0] + wsum[1] + wsum[2] + wsum[3]);
        __threadfence();
        tic = atomicAdd(&cnt[1], 1u);
    }
    __syncthreads();
    if (t == 0 && tic == 63u) {
        __threadfence();
        float a0 = atomicAdd(&acc[0], 0.f);
        float a1 = atomicAdd(&acc[1], 0.f);
        float a2 = atomicAdd(&acc[2], 0.f);
        float l1 = (a0 + a1) * (0.5f / 2048.f);
        float l2 = a2 * (1.f / 4096.f);
        out[0] = l1 + l2; out[1] = l1; out[2] = l2;
    }
}

extern "C" void kernel_launch(void* const* d_in, const int* in_sizes, int n_in,
                              void* d_out, int out_size, void* d_ws, size_t ws_size,
                              hipStream_t stream) {
    (void)in_sizes; (void)n_in; (void)out_size; (void)ws_size;
    const float* ref_points = (const float*)d_in[0];
    const float* src_points = (const float*)d_in[1];
    const float* ref_c      = (const float*)d_in[2];
    const float* src_c      = (const float*)d_in[3];
    const float* ref_f      = (const float*)d_in[4];
    const float* src_f      = (const float*)d_in[5];
    const int*   gti        = (const int*)d_in[6];
    const float* gtv        = (const float*)d_in[7];
    const float* spm        = (const float*)d_in[8];
    const int*   rbi        = (const int*)d_in[9];
    const int*   sbi        = (const int*)d_in[10];

    char* ws = (char*)d_ws;
    float4* rowp = (float4*)(ws + OFF_ROWP);
    float4* colp = (float4*)(ws + OFF_COLP);
    u32*   gtb  = (u32*)  (ws + OFF_GTB);
    u64*   nn   = (u64*)  (ws + OFF_NN);
    u64*   cand = (u64*)  (ws + OFF_CAND);
    float* acc  = (float*)(ws + OFF_ACC);
    u32*   cnt  = (u32*)  (ws + OFF_CNT);
    u32*   bm   = (u32*)  (ws + OFF_BM);
    u64*   hash = (u64*)  (ws + OFF_HASH);

    k_init <<<128, 256, 0, stream>>>((uint4*)gtb, nn, acc, hash, cnt, bm);
    k_nn   <<<dim3(256, 2), 256, 0, stream>>>(ref_points, src_points, ref_c, src_c,
                                              rbi, sbi, bm, nn);
    k_msc  <<<32, 256, 0, stream>>>(nn, bm, spm, gti, gtv, gtb, hash, cand, cnt, acc);
    k_gemm <<<dim3(32, 16), 256, 0, stream>>>(ref_f, src_f, spm, gtb, rowp, colp);
    k_merge<<<64, 256, 0, stream>>>(rowp, colp, acc, cnt, (float*)d_out);
}

// Round 21
// 110.969 us; speedup vs baseline: 1.0142x; 1.0142x over previous
//
#include <hip/hip_runtime.h>
#include <math.h>

using u8  = unsigned char;
using u32 = unsigned int;
using u64 = unsigned long long;

typedef short short8 __attribute__((ext_vector_type(8)));
typedef float f32x4  __attribute__((ext_vector_type(4)));
typedef float f32x2  __attribute__((ext_vector_type(2)));

#define MC 2048
#define NC 2048
#define DF 256
#define NFULL 50000
#define NBACK 30000
#define KCORR 4096
#define MAXPTS 256
#define NN_CHUNK 196   // 256 chunks * 196 = 50176 >= 50000; 49 groups of 4
#define BM_WORDS_I 1568

// ---------------- workspace layout ----------------
constexpr size_t OFF_ROWP = 0;                                // 64*2048 float4 = 2 MB
constexpr size_t OFF_COLP = (size_t)2 * 1024 * 1024;          // 32*2048 float4 = 1 MB
constexpr size_t OFF_GTB  = (size_t)3 * 1024 * 1024;          // 2048*64 u32 = 512 KB (bitfield)
constexpr size_t OFF_NN   = OFF_GTB + (size_t)512 * 1024;     // 4096 u64 = 32 KB
constexpr size_t OFF_CAND = OFF_NN + 4096 * 8;                // 4096 u64 = 32 KB
constexpr size_t OFF_ACC  = OFF_CAND + 4096 * 8;              // 8 f32
constexpr size_t OFF_CNT  = OFF_ACC + 256;                    // counters/tickets
constexpr size_t OFF_BM   = OFF_CNT + 256;                    // 2*1568 u32 = 12.5 KB
constexpr size_t OFF_HASH = OFF_BM + 3200 * 4;                // 8192 u64 = 64 KB

// cnt[] map: 0=cand count, 1=merge ticket, 2=mscA ticket, 3=mscB ticket

__device__ __forceinline__ u32 mask_of(const u64* nn, const u32* bm, int idx, int side) {
    u32 j = (u32)(nn[idx] & 0xFFFFFFFFull);
    return (bm[side * BM_WORDS_I + (j >> 5)] >> (j & 31)) & 1u;
}

__device__ __forceinline__ void circle_terms(float d, bool g, float& lp, float& ln) {
    if (g) { float a = d - 0.1f; lp = a > 0.f ? 24.f*a*a : 0.f; ln = 0.f; }
    else   { float b = 1.4f - d; ln = b > 0.f ? 24.f*b*b : 0.f; lp = 0.f; }
}

__device__ __forceinline__ float softplus_(float x) {
    return fmaxf(x, 0.f) + log1pf(expf(-fabsf(x)));
}

// online-LSE merge: (M,S) <- (M,S) + (M2,S2)
__device__ __forceinline__ void lse_merge(float& M, float& S, float M2, float S2) {
    float nm = fmaxf(M, M2);
    S = S * expf(M - nm) + S2 * expf(M2 - nm);
    M = nm;
}

// block-wide ticket barrier
__device__ __forceinline__ void block_barrier(u32* counter, u32 target, u32* s_tic) {
    __threadfence();
    __syncthreads();
    if (threadIdx.x == 0) {
        *s_tic = atomicAdd(counter, 1u);
        while (__hip_atomic_load(counter, __ATOMIC_ACQUIRE, __HIP_MEMORY_SCOPE_AGENT) < target) {}
    }
    __syncthreads();
}

// ---------------- init: zero gtb/hash/nn/bm/acc/cnt ----------------
__global__ __launch_bounds__(256) void k_init(uint4* __restrict__ gtb4, u64* __restrict__ nn,
                                              float* __restrict__ acc, u64* __restrict__ hash,
                                              u32* __restrict__ cnt, u32* __restrict__ bm) {
    int e = blockIdx.x * 256 + threadIdx.x;   // 0..32767
    gtb4[e] = make_uint4(0u, 0u, 0u, 0u);
    if (e < 8192) hash[e] = 0ull;
    if (e < 4096) nn[e] = ~0ull;
    if (e < 2 * BM_WORDS_I) bm[e] = 0u;
    if (e < 8) acc[e] = 0.f;
    if (e < 8) cnt[e] = 0u;
}

// ---------------- NN argmin: SoA-by-4 LDS, packed-f32, IPT=2, 8 blocks/CU ----------
// (R19 version — best measured; R20's IPT=8 at 2 blocks/CU was slightly worse)
__global__ __launch_bounds__(256) void k_nn(
        const float* __restrict__ fr, const float* __restrict__ fs,
        const float* __restrict__ cr, const float* __restrict__ cs,
        const int* __restrict__ rbi, const int* __restrict__ sbi,
        u32* __restrict__ bm, u64* __restrict__ nn) {
    const int side = blockIdx.y;
    const float* full = side ? fs : fr;
    const float* corr = side ? cs : cr;
    const int ib = blockIdx.x & 3, ch = blockIdx.x >> 2;
    const int t = threadIdx.x;

    // folded k_bm: 235*256 = 60160 >= 60000 entries (side-0 blocks only)
    int gb = side * 1024 + blockIdx.x;
    if (gb < 235) {
        int e = gb * 256 + t;
        if (e < 2 * NBACK) {
            int s2 = e < NBACK ? 0 : 1;
            int v = s2 ? sbi[e - NBACK] : rbi[e];
            atomicOr(&bm[s2 * BM_WORDS_I + (v >> 5)], 1u << (v & 31));
        }
    }

    __shared__ float4 sx4[49], sy4[49], sz4[49], sw4[49];
    const int j0 = ch * NN_CHUNK;
    if (t < 49) {
        int b4 = j0 + t * 4;
        float xx[4], yy[4], zz[4], ww[4];
        #pragma unroll
        for (int u = 0; u < 4; ++u) {
            int j = b4 + u;
            if (j < NFULL) {
                float x = full[j*3], y = full[j*3+1], z = full[j*3+2];
                xx[u] = x; yy[u] = y; zz[u] = z;
                ww[u] = fmaf(x, x, fmaf(y, y, z*z));
            } else {
                xx[u] = 0.f; yy[u] = 0.f; zz[u] = 0.f; ww[u] = 3.0e38f;  // sentinel
            }
        }
        sx4[t] = make_float4(xx[0], xx[1], xx[2], xx[3]);
        sy4[t] = make_float4(yy[0], yy[1], yy[2], yy[3]);
        sz4[t] = make_float4(zz[0], zz[1], zz[2], zz[3]);
        sw4[t] = make_float4(ww[0], ww[1], ww[2], ww[3]);
    }

    float ax[2], ay[2], az[2], bd[2];
    int bg[2];
    #pragma unroll
    for (int q = 0; q < 2; ++q) {
        int i = ib * 512 + q * 256 + t;
        float cx = corr[i*3], cy = corr[i*3+1], cz = corr[i*3+2];
        ax[q] = -2.f*cx; ay[q] = -2.f*cy; az[q] = -2.f*cz;
        bd[q] = 3.4e38f; bg[q] = 0;
    }
    __syncthreads();

    #pragma unroll 2
    for (int g = 0; g < 49; ++g) {
        float4 X = sx4[g], Y = sy4[g], Z = sz4[g], W = sw4[g];
        f32x2 xlo = {X.x, X.y}, xhi = {X.z, X.w};
        f32x2 ylo = {Y.x, Y.y}, yhi = {Y.z, Y.w};
        f32x2 zlo = {Z.x, Z.y}, zhi = {Z.z, Z.w};
        f32x2 wlo = {W.x, W.y}, whi = {W.z, W.w};
        #pragma unroll
        for (int q = 0; q < 2; ++q) {
            f32x2 aq = {ax[q], ax[q]}, bq = {ay[q], ay[q]}, cq2 = {az[q], az[q]};
            f32x2 dlo = __builtin_elementwise_fma(aq, xlo,
                          __builtin_elementwise_fma(bq, ylo,
                            __builtin_elementwise_fma(cq2, zlo, wlo)));
            f32x2 dhi = __builtin_elementwise_fma(aq, xhi,
                          __builtin_elementwise_fma(bq, yhi,
                            __builtin_elementwise_fma(cq2, zhi, whi)));
            f32x2 m2 = __builtin_elementwise_min(dlo, dhi);
            float gm = fminf(m2.x, m2.y);
            bool win = gm < bd[q];
            bd[q] = fminf(bd[q], gm);
            bg[q] = win ? g : bg[q];
        }
    }

    #pragma unroll
    for (int q = 0; q < 2; ++q) {
        int gsel = bg[q];
        float4 X = sx4[gsel], Y = sy4[gsel], Z = sz4[gsel], W = sw4[gsel];
        f32x2 xlo = {X.x, X.y}, xhi = {X.z, X.w};
        f32x2 ylo = {Y.x, Y.y}, yhi = {Y.z, Y.w};
        f32x2 zlo = {Z.x, Z.y}, zhi = {Z.z, Z.w};
        f32x2 wlo = {W.x, W.y}, whi = {W.z, W.w};
        f32x2 aq = {ax[q], ax[q]}, bq = {ay[q], ay[q]}, cq2 = {az[q], az[q]};
        f32x2 dlo = __builtin_elementwise_fma(aq, xlo,
                      __builtin_elementwise_fma(bq, ylo,
                        __builtin_elementwise_fma(cq2, zlo, wlo)));
        f32x2 dhi = __builtin_elementwise_fma(aq, xhi,
                      __builtin_elementwise_fma(bq, yhi,
                        __builtin_elementwise_fma(cq2, zhi, whi)));
        float dv[4] = {dlo.x, dlo.y, dhi.x, dhi.y};
        u32 bj = (u32)(j0 + gsel * 4);
        bool found = false;
        #pragma unroll
        for (int u = 0; u < 4; ++u) {
            if (!found && dv[u] == bd[q]) { bj = (u32)(j0 + gsel*4 + u); found = true; }
        }
        int i = ib * 512 + q * 256 + t;
        float cn = 0.25f * fmaf(ax[q], ax[q], fmaf(ay[q], ay[q], az[q]*az[q]));
        float bf = bd[q] + cn;
        u32 db = __float_as_uint(bf);
        db = (db & 0x80000000u) ? ~db : (db | 0x80000000u);
        atomicMin(&nn[side * 2048 + i], ((u64)db << 32) | bj);
    }
}

// ---------------- fused scatter chain: loss2(parallel)+scat1 | scat2 | top-cap -----
// 32 blocks x 256. R20 lesson: loss2 as ONE block's 16-iteration dependent
// nn->bm chain serialized ~30+ us of cross-XCD latency while 31 blocks spun.
// Now loss2 is spread over all 32 blocks (128 entries each, 1/thread -> chain
// of exactly 2 dependent loads) with atomicAdd reduction (order variance ~1e-4
// << 2.7e-2 threshold).
__global__ __launch_bounds__(256) void k_msc(
        const u64* __restrict__ nn, const u32* __restrict__ bm,
        const float* __restrict__ spm, const int* __restrict__ gti,
        const float* __restrict__ gtv,
        u32* __restrict__ gtb, u64* __restrict__ hash, u64* __restrict__ cand,
        u32* __restrict__ cnt, float* __restrict__ acc) {
    const int b = blockIdx.x, t = threadIdx.x;
    __shared__ u64 keys[4096];
    __shared__ u32 s_tic;
    __shared__ float red2[4];

    // ---- phase A1: loss2, parallel across all 32 blocks ----
    {
        float c = 0.f;
        if (t < 128) {
            int e = b * 128 + t;   // 0..4095
            c = fabsf((1.f - spm[e]) - (float)mask_of(nn, bm, e, e >> 11));
        }
        for (int o = 32; o; o >>= 1) c += __shfl_xor(c, o);
        if ((t & 63) == 0) red2[t >> 6] = c;
        __syncthreads();
        if (t == 0) atomicAdd(&acc[2], red2[0] + red2[1] + red2[2] + red2[3]);
    }

    // ---- phase A2: scat1 (blocks 0-15) ----
    if (b < 16) {
        int k = b * 256 + t;
        int xi = gti[2*k], yi = gti[2*k+1];
        u32 cell = (u32)(xi * 2048 + yi);
        u32 masked = mask_of(nn, bm, xi, 0) & mask_of(nn, bm, 2048 + yi, 1);
        if (masked) atomicOr(&gtb[xi * 64 + (yi >> 5)], 1u << (yi & 31));
        u64 val = ((u64)(cell + 1) << 13) | ((u64)masked << 12) | (u32)k;
        u32 h = (cell * 2654435761u) >> 19;
        while (true) {
            u64 cur = hash[h];
            if (cur == 0ull) cur = atomicCAS(&hash[h], 0ull, val);
            if (cur == 0ull) break;
            if ((cur >> 13) == (u64)(cell + 1)) { atomicMax(&hash[h], val); break; }
            h = (h + 1) & 8191;
        }
    }
    block_barrier(&cnt[2], 32u, &s_tic);

    // ---- phase B: scat2 (all 32 blocks) ----
    {
        int e = b * 256 + t;   // 0..8191
        u64 s = __hip_atomic_load(&hash[e], __ATOMIC_RELAXED, __HIP_MEMORY_SCOPE_AGENT);
        if (s != 0ull && ((s >> 12) & 1ull)) {
            u32 cell = (u32)(s >> 13) - 1u;
            u32 kk = (u32)(s & 0xFFFull);
            u32 vb = __float_as_uint(gtv[kk]);   // overlaps >= 0 -> bits monotonic
            u32 idx = atomicAdd(&cnt[0], 1u);
            cand[idx] = ((u64)vb << 22) | (u32)(0x3FFFFF - cell);
        }
    }
    block_barrier(&cnt[3], 32u, &s_tic);

    // ---- phase C: top-256 cap (blocks 0-15) ----
    if (b < 16) {
        const int n = (int)__hip_atomic_load(&cnt[0], __ATOMIC_RELAXED, __HIP_MEMORY_SCOPE_AGENT);
        if (n > MAXPTS && b * 256 < n) {
            for (int e = t; e < n; e += 256)
                keys[e] = __hip_atomic_load(&cand[e], __ATOMIC_RELAXED, __HIP_MEMORY_SCOPE_AGENT);
            __syncthreads();
            int c = b * 256 + t;
            if (c < n) {
                u64 me = keys[c];
                int rank = 0;
                #pragma unroll 4
                for (int j = 0; j < n; ++j) rank += (keys[j] > me);
                if (rank >= MAXPTS) {
                    u32 cell = 0x3FFFFFu - (u32)(me & 0x3FFFFFull);
                    int row = cell >> 11, col = cell & 2047;
                    atomicAnd(&gtb[row * 64 + (col >> 5)], ~(1u << (col & 31)));
                }
            }
        }
    }
}

// ---------------- fused MFMA bf16 GEMM + laplace + row/col LSE partials (R13) ------
__global__ __launch_bounds__(256) void k_gemm(
        const float* __restrict__ A, const float* __restrict__ B,
        const float* __restrict__ spm, const u32* __restrict__ gtb,
        float4* __restrict__ rowp, float4* __restrict__ colp) {
    __shared__ __align__(16) short As[16384];   // 32 KB
    __shared__ __align__(16) short Bs[8192];    // 16 KB
    __shared__ u32 gtw[256];                    // 1 KB
    const int t = threadIdx.x;
    const int l = t & 63, wid = t >> 6;
    const int wm = wid >> 1, wn = wid & 1;
    const int i0 = blockIdx.y * 128, j0 = blockIdx.x * 64;

    gtw[t] = gtb[(size_t)(i0 + (t >> 1)) * 64 + (j0 >> 5) + (t & 1)];

    f32x4 acc[4][2] = {};

    for (int ks = 0; ks < 2; ++ks) {
        __syncthreads();
        #pragma unroll
        for (int it = 0; it < 12; ++it) {
            int sl = it * 256 + t;                 // 0..3071 slots of 16B
            int c = sl & 63, q = c >> 4, r15 = c & 15;
            const float* src;
            short* dst;
            int kf;
            if (it < 8) {                          // A: slots 0..2047
                int frag = sl >> 6;                // mf(8) x kf(4)
                kf = frag & 3;
                int row = (frag >> 2) * 16 + r15;
                src = A + (size_t)(i0 + row) * 256;
                dst = &As[sl * 8];
            } else {                               // B: slots 2048..3071
                int sl2 = sl - 2048;
                int frag = sl2 >> 6;               // nf(4) x kf(4)
                kf = frag & 3;
                int row = (frag >> 2) * 16 + r15;
                src = B + (size_t)(j0 + row) * 256;
                dst = &Bs[sl2 * 8];
            }
            int col = ks * 128 + kf * 32 + q * 8;
            float4 v0 = *(const float4*)(src + col);
            float4 v1 = *(const float4*)(src + col + 4);
            u32 w0 = __builtin_amdgcn_perm(__float_as_uint(v0.y), __float_as_uint(v0.x), 0x07060302u);
            u32 w1 = __builtin_amdgcn_perm(__float_as_uint(v0.w), __float_as_uint(v0.z), 0x07060302u);
            u32 w2 = __builtin_amdgcn_perm(__float_as_uint(v1.y), __float_as_uint(v1.x), 0x07060302u);
            u32 w3 = __builtin_amdgcn_perm(__float_as_uint(v1.w), __float_as_uint(v1.z), 0x07060302u);
            *(uint4*)dst = make_uint4(w0, w1, w2, w3);
        }
        __syncthreads();

        #pragma unroll
        for (int kf = 0; kf < 4; ++kf) {
            short8 a[4], b[2];
            #pragma unroll
            for (int mi = 0; mi < 4; ++mi)
                a[mi] = *(const short8*)&As[(((wm*4 + mi)*4 + kf) << 9) + l*8];
            #pragma unroll
            for (int ni = 0; ni < 2; ++ni)
                b[ni] = *(const short8*)&Bs[(((wn*2 + ni)*4 + kf) << 9) + l*8];
            #pragma unroll
            for (int mi = 0; mi < 4; ++mi)
                #pragma unroll
                for (int ni = 0; ni < 2; ++ni)
                    acc[mi][ni] = __builtin_amdgcn_mfma_f32_16x16x32_bf16(
                        a[mi], b[ni], acc[mi][ni], 0, 0, 0);
        }
    }

    // epilogue: C/D layout col=lane&15, row=(lane>>4)*4+reg [m89-verified]
    const int cq = l >> 4, cr = l & 15;
    const int rows0 = i0 + wm * 64, cols0 = j0 + wn * 32;

    float vmj[2];
    #pragma unroll
    for (int ni = 0; ni < 2; ++ni) vmj[ni] = 1.f - spm[2048 + cols0 + ni*16 + cr];
    float vmi[4][4];
    #pragma unroll
    for (int mi = 0; mi < 4; ++mi)
        #pragma unroll
        for (int rr = 0; rr < 4; ++rr)
            vmi[mi][rr] = 1.f - spm[rows0 + mi*16 + cq*4 + rr];

    u32 gmask = 0;
    #pragma unroll
    for (int mi = 0; mi < 4; ++mi)
        #pragma unroll
        for (int rr = 0; rr < 4; ++rr) {
            u32 w = gtw[(wm*64 + mi*16 + cq*4 + rr) * 2 + wn];
            #pragma unroll
            for (int ni = 0; ni < 2; ++ni)
                if ((w >> (ni*16 + cr)) & 1u) gmask |= 1u << (mi*8 + ni*4 + rr);
        }
    #pragma unroll
    for (int mi = 0; mi < 4; ++mi)
        #pragma unroll
        for (int ni = 0; ni < 2; ++ni)
            #pragma unroll
            for (int rr = 0; rr < 4; ++rr) {
                float s  = acc[mi][ni][rr];
                float fs = fmaxf(2.f - 2.f*s, 0.f);
                acc[mi][ni][rr] = sqrtf(fs) * expf(0.5f * vmi[mi][rr] * vmj[ni]);
            }

    const int jt2 = blockIdx.x * 2 + wn;   // 0..63
    const int it2 = blockIdx.y * 2 + wm;   // 0..31

    #pragma unroll
    for (int mi = 0; mi < 4; ++mi)
        #pragma unroll
        for (int rr = 0; rr < 4; ++rr) {
            float lp0, ln0, lp1, ln1;
            circle_terms(acc[mi][0][rr], (gmask >> (mi*8 + rr)) & 1, lp0, ln0);
            circle_terms(acc[mi][1][rr], (gmask >> (mi*8 + 4 + rr)) & 1, lp1, ln1);
            float mp = fmaxf(lp0, lp1), mn = fmaxf(ln0, ln1);
            #pragma unroll
            for (int o = 1; o < 16; o <<= 1) {
                mp = fmaxf(mp, __shfl_xor(mp, o));
                mn = fmaxf(mn, __shfl_xor(mn, o));
            }
            float sp = expf(lp0 - mp) + expf(lp1 - mp);
            float sn = expf(ln0 - mn) + expf(ln1 - mn);
            #pragma unroll
            for (int o = 1; o < 16; o <<= 1) {
                sp += __shfl_xor(sp, o);
                sn += __shfl_xor(sn, o);
            }
            if (cr == mi*4 + rr) {
                int row = rows0 + mi*16 + cq*4 + rr;
                rowp[(size_t)jt2 * 2048 + row] = make_float4(mp, sp, mn, sn);
            }
        }

    #pragma unroll
    for (int ni = 0; ni < 2; ++ni) {
        float lp[16], ln[16];
        #pragma unroll
        for (int mi = 0; mi < 4; ++mi)
            #pragma unroll
            for (int rr = 0; rr < 4; ++rr)
                circle_terms(acc[mi][ni][rr], (gmask >> (mi*8 + ni*4 + rr)) & 1,
                             lp[mi*4+rr], ln[mi*4+rr]);
        float mp = lp[0], mn = ln[0];
        #pragma unroll
        for (int e = 1; e < 16; ++e) { mp = fmaxf(mp, lp[e]); mn = fmaxf(mn, ln[e]); }
        #pragma unroll
        for (int o = 16; o < 64; o <<= 1) {
            mp = fmaxf(mp, __shfl_xor(mp, o));
            mn = fmaxf(mn, __shfl_xor(mn, o));
        }
        float sp = 0.f, sn = 0.f;
        #pragma unroll
        for (int e = 0; e < 16; ++e) { sp += expf(lp[e] - mp); sn += expf(ln[e] - mn); }
        #pragma unroll
        for (int o = 16; o < 64; o <<= 1) {
            sp += __shfl_xor(sp, o);
            sn += __shfl_xor(sn, o);
        }
        if (cq == 0) {
            int col = cols0 + ni*16 + cr;
            colp[(size_t)it2 * 2048 + col] = make_float4(mp, sp, mn, sn);
        }
    }
}

// ---------------- merge partials: 64 blocks, 4 threads/element (R18, proven) ------
__global__ __launch_bounds__(256) void k_merge(const float4* __restrict__ rowp,
                                               const float4* __restrict__ colp,
                                               float* __restrict__ acc,
                                               u32* __restrict__ cnt,
                                               float* __restrict__ out) {
    const int t = threadIdx.x;
    const int b = blockIdx.x;    // 0..63
    const int sub = t & 3;
    float Mp = -1e30f, Sp = 0.f, Mn = -1e30f, Sn = 0.f;

    if (b < 32) {
        int row = (b * 256 + t) >> 2;           // 0..2047
        int base = sub * 16;
        #pragma unroll
        for (int j = 0; j < 16; j += 8) {
            float4 pb[8];
            #pragma unroll
            for (int u = 0; u < 8; ++u)
                pb[u] = rowp[(size_t)(base + j + u) * 2048 + row];
            #pragma unroll
            for (int u = 0; u < 8; ++u) {
                lse_merge(Mp, Sp, pb[u].x, pb[u].y);
                lse_merge(Mn, Sn, pb[u].z, pb[u].w);
            }
        }
    } else {
        int col = ((b - 32) * 256 + t) >> 2;    // 0..2047
        int base = sub * 8;
        float4 pb[8];
        #pragma unroll
        for (int u = 0; u < 8; ++u)
            pb[u] = colp[(size_t)(base + u) * 2048 + col];
        #pragma unroll
        for (int u = 0; u < 8; ++u) {
            lse_merge(Mp, Sp, pb[u].x, pb[u].y);
            lse_merge(Mn, Sn, pb[u].z, pb[u].w);
        }
    }

    #pragma unroll
    for (int o = 1; o < 4; o <<= 1) {
        float M2 = __shfl_xor(Mp, o), S2 = __shfl_xor(Sp, o);
        lse_merge(Mp, Sp, M2, S2);
        M2 = __shfl_xor(Mn, o); S2 = __shfl_xor(Sn, o);
        lse_merge(Mn, Sn, M2, S2);
    }

    float lv = 0.f;
    if (sub == 0) {
        float x = (Mp + logf(Sp)) + (Mn + logf(Sn));
        lv = softplus_(x) * (1.f / 24.f);
    }
    for (int o = 32; o; o >>= 1) lv += __shfl_xor(lv, o);
    __shared__ float wsum[4];
    __shared__ u32 tic;
    if ((t & 63) == 0) wsum[t >> 6] = lv;
    __syncthreads();
    if (t == 0) {
        atomicAdd(&acc[b < 32 ? 0 : 1], wsum[0] + wsum[1] + wsum[2] + wsum[3]);
        __threadfence();
        tic = atomicAdd(&cnt[1], 1u);
    }
    __syncthreads();
    if (t == 0 && tic == 63u) {
        __threadfence();
        float a0 = atomicAdd(&acc[0], 0.f);
        float a1 = atomicAdd(&acc[1], 0.f);
        float a2 = atomicAdd(&acc[2], 0.f);
        float l1 = (a0 + a1) * (0.5f / 2048.f);
        float l2 = a2 * (1.f / 4096.f);
        out[0] = l1 + l2; out[1] = l1; out[2] = l2;
    }
}

extern "C" void kernel_launch(void* const* d_in, const int* in_sizes, int n_in,
                              void* d_out, int out_size, void* d_ws, size_t ws_size,
                              hipStream_t stream) {
    (void)in_sizes; (void)n_in; (void)out_size; (void)ws_size;
    const float* ref_points = (const float*)d_in[0];
    const float* src_points = (const float*)d_in[1];
    const float* ref_c      = (const float*)d_in[2];
    const float* src_c      = (const float*)d_in[3];
    const float* ref_f      = (const float*)d_in[4];
    const float* src_f      = (const float*)d_in[5];
    const int*   gti        = (const int*)d_in[6];
    const float* gtv        = (const float*)d_in[7];
    const float* spm        = (const float*)d_in[8];
    const int*   rbi        = (const int*)d_in[9];
    const int*   sbi        = (const int*)d_in[10];

    char* ws = (char*)d_ws;
    float4* rowp = (float4*)(ws + OFF_ROWP);
    float4* colp = (float4*)(ws + OFF_COLP);
    u32*   gtb  = (u32*)  (ws + OFF_GTB);
    u64*   nn   = (u64*)  (ws + OFF_NN);
    u64*   cand = (u64*)  (ws + OFF_CAND);
    float* acc  = (float*)(ws + OFF_ACC);
    u32*   cnt  = (u32*)  (ws + OFF_CNT);
    u32*   bm   = (u32*)  (ws + OFF_BM);
    u64*   hash = (u64*)  (ws + OFF_HASH);

    k_init <<<128, 256, 0, stream>>>((uint4*)gtb, nn, acc, hash, cnt, bm);
    k_nn   <<<dim3(1024, 2), 256, 0, stream>>>(ref_points, src_points, ref_c, src_c,
                                               rbi, sbi, bm, nn);
    k_msc  <<<32, 256, 0, stream>>>(nn, bm, spm, gti, gtv, gtb, hash, cand, cnt, acc);
    k_gemm <<<dim3(32, 16), 256, 0, stream>>>(ref_f, src_f, spm, gtb, rowp, colp);
    k_merge<<<64, 256, 0, stream>>>(rowp, colp, acc, cnt, (float*)d_out);
}

// Round 22
// 101.262 us; speedup vs baseline: 1.1114x; 1.0959x over previous
//
#include <hip/hip_runtime.h>
#include <math.h>

using u8  = unsigned char;
using u32 = unsigned int;
using u64 = unsigned long long;

typedef short short8 __attribute__((ext_vector_type(8)));
typedef float f32x4  __attribute__((ext_vector_type(4)));
typedef float f32x2  __attribute__((ext_vector_type(2)));

#define MC 2048
#define NC 2048
#define DF 256
#define NFULL 50000
#define NBACK 30000
#define KCORR 4096
#define MAXPTS 256
#define NN_CHUNK 196   // 256 chunks * 196 = 50176 >= 50000; 49 groups of 4
#define BM_WORDS_I 1568

// ---------------- workspace layout ----------------
constexpr size_t OFF_ROWP = 0;                                // 64*2048 float4 = 2 MB
constexpr size_t OFF_COLP = (size_t)2 * 1024 * 1024;          // 32*2048 float4 = 1 MB
constexpr size_t OFF_GTB  = (size_t)3 * 1024 * 1024;          // 2048*64 u32 = 512 KB (bitfield)
constexpr size_t OFF_NN   = OFF_GTB + (size_t)512 * 1024;     // 4096 u64 = 32 KB
constexpr size_t OFF_CAND = OFF_NN + 4096 * 8;                // 4096 u64 = 32 KB
constexpr size_t OFF_ACC  = OFF_CAND + 4096 * 8;              // 8 f32
constexpr size_t OFF_CNT  = OFF_ACC + 256;                    // counters/tickets
constexpr size_t OFF_BM   = OFF_CNT + 256;                    // 2*1568 u32 = 12.5 KB
constexpr size_t OFF_KMAX = (size_t)4 * 1024 * 1024;          // 4M u32 = 16 MB (per-cell max-k)

// cnt[] map: 0=cand count, 1=merge ticket, 2=mscA ticket, 3=mscB ticket

__device__ __forceinline__ u32 mask_of(const u64* nn, const u32* bm, int idx, int side) {
    u32 j = (u32)(nn[idx] & 0xFFFFFFFFull);
    return (bm[side * BM_WORDS_I + (j >> 5)] >> (j & 31)) & 1u;
}

__device__ __forceinline__ void circle_terms(float d, bool g, float& lp, float& ln) {
    if (g) { float a = d - 0.1f; lp = a > 0.f ? 24.f*a*a : 0.f; ln = 0.f; }
    else   { float b = 1.4f - d; ln = b > 0.f ? 24.f*b*b : 0.f; lp = 0.f; }
}

__device__ __forceinline__ float softplus_(float x) {
    return fmaxf(x, 0.f) + log1pf(expf(-fabsf(x)));
}

// online-LSE merge: (M,S) <- (M,S) + (M2,S2)
__device__ __forceinline__ void lse_merge(float& M, float& S, float M2, float S2) {
    float nm = fmaxf(M, M2);
    S = S * expf(M - nm) + S2 * expf(M2 - nm);
    M = nm;
}

// block-wide ticket barrier
__device__ __forceinline__ void block_barrier(u32* counter, u32 target, u32* s_tic) {
    __threadfence();
    __syncthreads();
    if (threadIdx.x == 0) {
        *s_tic = atomicAdd(counter, 1u);
        while (__hip_atomic_load(counter, __ATOMIC_ACQUIRE, __HIP_MEMORY_SCOPE_AGENT) < target) {}
    }
    __syncthreads();
}

// ---------------- init: zero kmax(16MB)/gtb/nn/bm/acc/cnt ----------------
__global__ __launch_bounds__(256) void k_init(uint4* __restrict__ gtb4, u64* __restrict__ nn,
                                              float* __restrict__ acc, u32* __restrict__ cnt,
                                              u32* __restrict__ bm, uint4* __restrict__ kmax4) {
    int e = blockIdx.x * 256 + threadIdx.x;   // 0..262143
    #pragma unroll
    for (int u = 0; u < 4; ++u)
        kmax4[e + u * 262144] = make_uint4(0u, 0u, 0u, 0u);   // 4M u32
    if (e < 32768) gtb4[e] = make_uint4(0u, 0u, 0u, 0u);
    if (e < 4096) nn[e] = ~0ull;
    if (e < 2 * BM_WORDS_I) bm[e] = 0u;
    if (e < 8) acc[e] = 0.f;
    if (e < 8) cnt[e] = 0u;
}

// ---------------- NN argmin: SoA-by-4 LDS, packed-f32, IPT=2, 8 blocks/CU (R19) ----
__global__ __launch_bounds__(256) void k_nn(
        const float* __restrict__ fr, const float* __restrict__ fs,
        const float* __restrict__ cr, const float* __restrict__ cs,
        const int* __restrict__ rbi, const int* __restrict__ sbi,
        u32* __restrict__ bm, u64* __restrict__ nn) {
    const int side = blockIdx.y;
    const float* full = side ? fs : fr;
    const float* corr = side ? cs : cr;
    const int ib = blockIdx.x & 3, ch = blockIdx.x >> 2;
    const int t = threadIdx.x;

    // folded k_bm: 235*256 = 60160 >= 60000 entries (side-0 blocks only)
    int gb = side * 1024 + blockIdx.x;
    if (gb < 235) {
        int e = gb * 256 + t;
        if (e < 2 * NBACK) {
            int s2 = e < NBACK ? 0 : 1;
            int v = s2 ? sbi[e - NBACK] : rbi[e];
            atomicOr(&bm[s2 * BM_WORDS_I + (v >> 5)], 1u << (v & 31));
        }
    }

    __shared__ float4 sx4[49], sy4[49], sz4[49], sw4[49];
    const int j0 = ch * NN_CHUNK;
    if (t < 49) {
        int b4 = j0 + t * 4;
        float xx[4], yy[4], zz[4], ww[4];
        #pragma unroll
        for (int u = 0; u < 4; ++u) {
            int j = b4 + u;
            if (j < NFULL) {
                float x = full[j*3], y = full[j*3+1], z = full[j*3+2];
                xx[u] = x; yy[u] = y; zz[u] = z;
                ww[u] = fmaf(x, x, fmaf(y, y, z*z));
            } else {
                xx[u] = 0.f; yy[u] = 0.f; zz[u] = 0.f; ww[u] = 3.0e38f;  // sentinel
            }
        }
        sx4[t] = make_float4(xx[0], xx[1], xx[2], xx[3]);
        sy4[t] = make_float4(yy[0], yy[1], yy[2], yy[3]);
        sz4[t] = make_float4(zz[0], zz[1], zz[2], zz[3]);
        sw4[t] = make_float4(ww[0], ww[1], ww[2], ww[3]);
    }

    float ax[2], ay[2], az[2], bd[2];
    int bg[2];
    #pragma unroll
    for (int q = 0; q < 2; ++q) {
        int i = ib * 512 + q * 256 + t;
        float cx = corr[i*3], cy = corr[i*3+1], cz = corr[i*3+2];
        ax[q] = -2.f*cx; ay[q] = -2.f*cy; az[q] = -2.f*cz;
        bd[q] = 3.4e38f; bg[q] = 0;
    }
    __syncthreads();

    #pragma unroll 2
    for (int g = 0; g < 49; ++g) {
        float4 X = sx4[g], Y = sy4[g], Z = sz4[g], W = sw4[g];
        f32x2 xlo = {X.x, X.y}, xhi = {X.z, X.w};
        f32x2 ylo = {Y.x, Y.y}, yhi = {Y.z, Y.w};
        f32x2 zlo = {Z.x, Z.y}, zhi = {Z.z, Z.w};
        f32x2 wlo = {W.x, W.y}, whi = {W.z, W.w};
        #pragma unroll
        for (int q = 0; q < 2; ++q) {
            f32x2 aq = {ax[q], ax[q]}, bq = {ay[q], ay[q]}, cq2 = {az[q], az[q]};
            f32x2 dlo = __builtin_elementwise_fma(aq, xlo,
                          __builtin_elementwise_fma(bq, ylo,
                            __builtin_elementwise_fma(cq2, zlo, wlo)));
            f32x2 dhi = __builtin_elementwise_fma(aq, xhi,
                          __builtin_elementwise_fma(bq, yhi,
                            __builtin_elementwise_fma(cq2, zhi, whi)));
            f32x2 m2 = __builtin_elementwise_min(dlo, dhi);
            float gm = fminf(m2.x, m2.y);
            bool win = gm < bd[q];
            bd[q] = fminf(bd[q], gm);
            bg[q] = win ? g : bg[q];
        }
    }

    #pragma unroll
    for (int q = 0; q < 2; ++q) {
        int gsel = bg[q];
        float4 X = sx4[gsel], Y = sy4[gsel], Z = sz4[gsel], W = sw4[gsel];
        f32x2 xlo = {X.x, X.y}, xhi = {X.z, X.w};
        f32x2 ylo = {Y.x, Y.y}, yhi = {Y.z, Y.w};
        f32x2 zlo = {Z.x, Z.y}, zhi = {Z.z, Z.w};
        f32x2 wlo = {W.x, W.y}, whi = {W.z, W.w};
        f32x2 aq = {ax[q], ax[q]}, bq = {ay[q], ay[q]}, cq2 = {az[q], az[q]};
        f32x2 dlo = __builtin_elementwise_fma(aq, xlo,
                      __builtin_elementwise_fma(bq, ylo,
                        __builtin_elementwise_fma(cq2, zlo, wlo)));
        f32x2 dhi = __builtin_elementwise_fma(aq, xhi,
                      __builtin_elementwise_fma(bq, yhi,
                        __builtin_elementwise_fma(cq2, zhi, whi)));
        float dv[4] = {dlo.x, dlo.y, dhi.x, dhi.y};
        u32 bj = (u32)(j0 + gsel * 4);
        bool found = false;
        #pragma unroll
        for (int u = 0; u < 4; ++u) {
            if (!found && dv[u] == bd[q]) { bj = (u32)(j0 + gsel*4 + u); found = true; }
        }
        int i = ib * 512 + q * 256 + t;
        float cn = 0.25f * fmaf(ax[q], ax[q], fmaf(ay[q], ay[q], az[q]*az[q]));
        float bf = bd[q] + cn;
        u32 db = __float_as_uint(bf);
        db = (db & 0x80000000u) ? ~db : (db | 0x80000000u);
        atomicMin(&nn[side * 2048 + i], ((u64)db << 32) | bj);
    }
}

// ---------------- fused scatter chain: direct-mapped kmax dedup (no hash) ----------
// 32 blocks x 256. R21 lesson: the hash insert's variable-length linear-probe
// chain of cross-XCD atomicCAS (~1us each, worst cluster 20-40 probes) was the
// ~39us cost in every structure since R13. Replaced with ONE fire-and-forget
// atomicMax(kmax[cell], k+1) per entry (no probe chain); winners are
// kmax[cell]==k+1. cell/masked stay in registers between phases.
__global__ __launch_bounds__(256) void k_msc(
        const u64* __restrict__ nn, const u32* __restrict__ bm,
        const float* __restrict__ spm, const int* __restrict__ gti,
        const float* __restrict__ gtv,
        u32* __restrict__ gtb, u32* __restrict__ kmax, u64* __restrict__ cand,
        u32* __restrict__ cnt, float* __restrict__ acc) {
    const int b = blockIdx.x, t = threadIdx.x;
    __shared__ u64 keys[4096];
    __shared__ u32 s_tic;
    __shared__ float red2[4];

    // ---- phase A: loss2 + gtb bit-set + kmax dedup (t<128; e = entry 0..4095) ----
    const int e = b * 128 + t;
    float c = 0.f;
    u32 cell = 0, masked = 0;
    if (t < 128) {
        c = fabsf((1.f - spm[e]) - (float)mask_of(nn, bm, e, e >> 11));
        int xi = gti[2*e], yi = gti[2*e+1];
        cell = (u32)(xi * 2048 + yi);
        masked = mask_of(nn, bm, xi, 0) & mask_of(nn, bm, 2048 + yi, 1);
        if (masked) atomicOr(&gtb[xi * 64 + (yi >> 5)], 1u << (yi & 31));
        atomicMax(&kmax[cell], (u32)e + 1u);   // last-wins = max k per cell
    }
    for (int o = 32; o; o >>= 1) c += __shfl_xor(c, o);
    if ((t & 63) == 0) red2[t >> 6] = c;
    __syncthreads();
    if (t == 0) atomicAdd(&acc[2], red2[0] + red2[1] + red2[2] + red2[3]);

    block_barrier(&cnt[2], 32u, &s_tic);

    // ---- phase B: collect winners (one load, no chain) ----
    if (t < 128) {
        u32 wk = __hip_atomic_load(&kmax[cell], __ATOMIC_RELAXED, __HIP_MEMORY_SCOPE_AGENT);
        if (masked && wk == (u32)e + 1u) {
            u32 vb = __float_as_uint(gtv[e]);   // overlaps >= 0 -> bits monotonic
            u32 idx = atomicAdd(&cnt[0], 1u);
            cand[idx] = ((u64)vb << 22) | (u32)(0x3FFFFF - cell);
        }
    }
    block_barrier(&cnt[3], 32u, &s_tic);

    // ---- phase C: top-256 cap (blocks 0-15) ----
    if (b < 16) {
        const int n = (int)__hip_atomic_load(&cnt[0], __ATOMIC_RELAXED, __HIP_MEMORY_SCOPE_AGENT);
        if (n > MAXPTS && b * 256 < n) {
            for (int e2 = t; e2 < n; e2 += 256)
                keys[e2] = __hip_atomic_load(&cand[e2], __ATOMIC_RELAXED, __HIP_MEMORY_SCOPE_AGENT);
            __syncthreads();
            int c2 = b * 256 + t;
            if (c2 < n) {
                u64 me = keys[c2];
                int rank = 0;
                #pragma unroll 4
                for (int j = 0; j < n; ++j) rank += (keys[j] > me);
                if (rank >= MAXPTS) {
                    u32 cl = 0x3FFFFFu - (u32)(me & 0x3FFFFFull);
                    int row = cl >> 11, col = cl & 2047;
                    atomicAnd(&gtb[row * 64 + (col >> 5)], ~(1u << (col & 31)));
                }
            }
        }
    }
}

// ---------------- fused MFMA bf16 GEMM + laplace + row/col LSE partials (R13) ------
__global__ __launch_bounds__(256) void k_gemm(
        const float* __restrict__ A, const float* __restrict__ B,
        const float* __restrict__ spm, const u32* __restrict__ gtb,
        float4* __restrict__ rowp, float4* __restrict__ colp) {
    __shared__ __align__(16) short As[16384];   // 32 KB
    __shared__ __align__(16) short Bs[8192];    // 16 KB
    __shared__ u32 gtw[256];                    // 1 KB
    const int t = threadIdx.x;
    const int l = t & 63, wid = t >> 6;
    const int wm = wid >> 1, wn = wid & 1;
    const int i0 = blockIdx.y * 128, j0 = blockIdx.x * 64;

    gtw[t] = gtb[(size_t)(i0 + (t >> 1)) * 64 + (j0 >> 5) + (t & 1)];

    f32x4 acc[4][2] = {};

    for (int ks = 0; ks < 2; ++ks) {
        __syncthreads();
        #pragma unroll
        for (int it = 0; it < 12; ++it) {
            int sl = it * 256 + t;                 // 0..3071 slots of 16B
            int c = sl & 63, q = c >> 4, r15 = c & 15;
            const float* src;
            short* dst;
            int kf;
            if (it < 8) {                          // A: slots 0..2047
                int frag = sl >> 6;                // mf(8) x kf(4)
                kf = frag & 3;
                int row = (frag >> 2) * 16 + r15;
                src = A + (size_t)(i0 + row) * 256;
                dst = &As[sl * 8];
            } else {                               // B: slots 2048..3071
                int sl2 = sl - 2048;
                int frag = sl2 >> 6;               // nf(4) x kf(4)
                kf = frag & 3;
                int row = (frag >> 2) * 16 + r15;
                src = B + (size_t)(j0 + row) * 256;
                dst = &Bs[sl2 * 8];
            }
            int col = ks * 128 + kf * 32 + q * 8;
            float4 v0 = *(const float4*)(src + col);
            float4 v1 = *(const float4*)(src + col + 4);
            u32 w0 = __builtin_amdgcn_perm(__float_as_uint(v0.y), __float_as_uint(v0.x), 0x07060302u);
            u32 w1 = __builtin_amdgcn_perm(__float_as_uint(v0.w), __float_as_uint(v0.z), 0x07060302u);
            u32 w2 = __builtin_amdgcn_perm(__float_as_uint(v1.y), __float_as_uint(v1.x), 0x07060302u);
            u32 w3 = __builtin_amdgcn_perm(__float_as_uint(v1.w), __float_as_uint(v1.z), 0x07060302u);
            *(uint4*)dst = make_uint4(w0, w1, w2, w3);
        }
        __syncthreads();

        #pragma unroll
        for (int kf = 0; kf < 4; ++kf) {
            short8 a[4], b[2];
            #pragma unroll
            for (int mi = 0; mi < 4; ++mi)
                a[mi] = *(const short8*)&As[(((wm*4 + mi)*4 + kf) << 9) + l*8];
            #pragma unroll
            for (int ni = 0; ni < 2; ++ni)
                b[ni] = *(const short8*)&Bs[(((wn*2 + ni)*4 + kf) << 9) + l*8];
            #pragma unroll
            for (int mi = 0; mi < 4; ++mi)
                #pragma unroll
                for (int ni = 0; ni < 2; ++ni)
                    acc[mi][ni] = __builtin_amdgcn_mfma_f32_16x16x32_bf16(
                        a[mi], b[ni], acc[mi][ni], 0, 0, 0);
        }
    }

    // epilogue: C/D layout col=lane&15, row=(lane>>4)*4+reg [m89-verified]
    const int cq = l >> 4, cr = l & 15;
    const int rows0 = i0 + wm * 64, cols0 = j0 + wn * 32;

    float vmj[2];
    #pragma unroll
    for (int ni = 0; ni < 2; ++ni) vmj[ni] = 1.f - spm[2048 + cols0 + ni*16 + cr];
    float vmi[4][4];
    #pragma unroll
    for (int mi = 0; mi < 4; ++mi)
        #pragma unroll
        for (int rr = 0; rr < 4; ++rr)
            vmi[mi][rr] = 1.f - spm[rows0 + mi*16 + cq*4 + rr];

    u32 gmask = 0;
    #pragma unroll
    for (int mi = 0; mi < 4; ++mi)
        #pragma unroll
        for (int rr = 0; rr < 4; ++rr) {
            u32 w = gtw[(wm*64 + mi*16 + cq*4 + rr) * 2 + wn];
            #pragma unroll
            for (int ni = 0; ni < 2; ++ni)
                if ((w >> (ni*16 + cr)) & 1u) gmask |= 1u << (mi*8 + ni*4 + rr);
        }
    #pragma unroll
    for (int mi = 0; mi < 4; ++mi)
        #pragma unroll
        for (int ni = 0; ni < 2; ++ni)
            #pragma unroll
            for (int rr = 0; rr < 4; ++rr) {
                float s  = acc[mi][ni][rr];
                float fs = fmaxf(2.f - 2.f*s, 0.f);
                acc[mi][ni][rr] = sqrtf(fs) * expf(0.5f * vmi[mi][rr] * vmj[ni]);
            }

    const int jt2 = blockIdx.x * 2 + wn;   // 0..63
    const int it2 = blockIdx.y * 2 + wm;   // 0..31

    #pragma unroll
    for (int mi = 0; mi < 4; ++mi)
        #pragma unroll
        for (int rr = 0; rr < 4; ++rr) {
            float lp0, ln0, lp1, ln1;
            circle_terms(acc[mi][0][rr], (gmask >> (mi*8 + rr)) & 1, lp0, ln0);
            circle_terms(acc[mi][1][rr], (gmask >> (mi*8 + 4 + rr)) & 1, lp1, ln1);
            float mp = fmaxf(lp0, lp1), mn = fmaxf(ln0, ln1);
            #pragma unroll
            for (int o = 1; o < 16; o <<= 1) {
                mp = fmaxf(mp, __shfl_xor(mp, o));
                mn = fmaxf(mn, __shfl_xor(mn, o));
            }
            float sp = expf(lp0 - mp) + expf(lp1 - mp);
            float sn = expf(ln0 - mn) + expf(ln1 - mn);
            #pragma unroll
            for (int o = 1; o < 16; o <<= 1) {
                sp += __shfl_xor(sp, o);
                sn += __shfl_xor(sn, o);
            }
            if (cr == mi*4 + rr) {
                int row = rows0 + mi*16 + cq*4 + rr;
                rowp[(size_t)jt2 * 2048 + row] = make_float4(mp, sp, mn, sn);
            }
        }

    #pragma unroll
    for (int ni = 0; ni < 2; ++ni) {
        float lp[16], ln[16];
        #pragma unroll
        for (int mi = 0; mi < 4; ++mi)
            #pragma unroll
            for (int rr = 0; rr < 4; ++rr)
                circle_terms(acc[mi][ni][rr], (gmask >> (mi*8 + ni*4 + rr)) & 1,
                             lp[mi*4+rr], ln[mi*4+rr]);
        float mp = lp[0], mn = ln[0];
        #pragma unroll
        for (int e = 1; e < 16; ++e) { mp = fmaxf(mp, lp[e]); mn = fmaxf(mn, ln[e]); }
        #pragma unroll
        for (int o = 16; o < 64; o <<= 1) {
            mp = fmaxf(mp, __shfl_xor(mp, o));
            mn = fmaxf(mn, __shfl_xor(mn, o));
        }
        float sp = 0.f, sn = 0.f;
        #pragma unroll
        for (int e = 0; e < 16; ++e) { sp += expf(lp[e] - mp); sn += expf(ln[e] - mn); }
        #pragma unroll
        for (int o = 16; o < 64; o <<= 1) {
            sp += __shfl_xor(sp, o);
            sn += __shfl_xor(sn, o);
        }
        if (cq == 0) {
            int col = cols0 + ni*16 + cr;
            colp[(size_t)it2 * 2048 + col] = make_float4(mp, sp, mn, sn);
        }
    }
}

// ---------------- merge partials: 64 blocks, 4 threads/element (R18, proven) ------
__global__ __launch_bounds__(256) void k_merge(const float4* __restrict__ rowp,
                                               const float4* __restrict__ colp,
                                               float* __restrict__ acc,
                                               u32* __restrict__ cnt,
                                               float* __restrict__ out) {
    const int t = threadIdx.x;
    const int b = blockIdx.x;    // 0..63
    const int sub = t & 3;
    float Mp = -1e30f, Sp = 0.f, Mn = -1e30f, Sn = 0.f;

    if (b < 32) {
        int row = (b * 256 + t) >> 2;           // 0..2047
        int base = sub * 16;
        #pragma unroll
        for (int j = 0; j < 16; j += 8) {
            float4 pb[8];
            #pragma unroll
            for (int u = 0; u < 8; ++u)
                pb[u] = rowp[(size_t)(base + j + u) * 2048 + row];
            #pragma unroll
            for (int u = 0; u < 8; ++u) {
                lse_merge(Mp, Sp, pb[u].x, pb[u].y);
                lse_merge(Mn, Sn, pb[u].z, pb[u].w);
            }
        }
    } else {
        int col = ((b - 32) * 256 + t) >> 2;    // 0..2047
        int base = sub * 8;
        float4 pb[8];
        #pragma unroll
        for (int u = 0; u < 8; ++u)
            pb[u] = colp[(size_t)(base + u) * 2048 + col];
        #pragma unroll
        for (int u = 0; u < 8; ++u) {
            lse_merge(Mp, Sp, pb[u].x, pb[u].y);
            lse_merge(Mn, Sn, pb[u].z, pb[u].w);
        }
    }

    #pragma unroll
    for (int o = 1; o < 4; o <<= 1) {
        float M2 = __shfl_xor(Mp, o), S2 = __shfl_xor(Sp, o);
        lse_merge(Mp, Sp, M2, S2);
        M2 = __shfl_xor(Mn, o); S2 = __shfl_xor(Sn, o);
        lse_merge(Mn, Sn, M2, S2);
    }

    float lv = 0.f;
    if (sub == 0) {
        float x = (Mp + logf(Sp)) + (Mn + logf(Sn));
        lv = softplus_(x) * (1.f / 24.f);
    }
    for (int o = 32; o; o >>= 1) lv += __shfl_xor(lv, o);
    __shared__ float wsum[4];
    __shared__ u32 tic;
    if ((t & 63) == 0) wsum[t >> 6] = lv;
    __syncthreads();
    if (t == 0) {
        atomicAdd(&acc[b < 32 ? 0 : 1], wsum[0] + wsum[1] + wsum[2] + wsum[3]);
        __threadfence();
        tic = atomicAdd(&cnt[1], 1u);
    }
    __syncthreads();
    if (t == 0 && tic == 63u) {
        __threadfence();
        float a0 = atomicAdd(&acc[0], 0.f);
        float a1 = atomicAdd(&acc[1], 0.f);
        float a2 = atomicAdd(&acc[2], 0.f);
        float l1 = (a0 + a1) * (0.5f / 2048.f);
        float l2 = a2 * (1.f / 4096.f);
        out[0] = l1 + l2; out[1] = l1; out[2] = l2;
    }
}

extern "C" void kernel_launch(void* const* d_in, const int* in_sizes, int n_in,
                              void* d_out, int out_size, void* d_ws, size_t ws_size,
                              hipStream_t stream) {
    (void)in_sizes; (void)n_in; (void)out_size; (void)ws_size;
    const float* ref_points = (const float*)d_in[0];
    const float* src_points = (const float*)d_in[1];
    const float* ref_c      = (const float*)d_in[2];
    const float* src_c      = (const float*)d_in[3];
    const float* ref_f      = (const float*)d_in[4];
    const float* src_f      = (const float*)d_in[5];
    const int*   gti        = (const int*)d_in[6];
    const float* gtv        = (const float*)d_in[7];
    const float* spm        = (const float*)d_in[8];
    const int*   rbi        = (const int*)d_in[9];
    const int*   sbi        = (const int*)d_in[10];

    char* ws = (char*)d_ws;
    float4* rowp = (float4*)(ws + OFF_ROWP);
    float4* colp = (float4*)(ws + OFF_COLP);
    u32*   gtb  = (u32*)  (ws + OFF_GTB);
    u64*   nn   = (u64*)  (ws + OFF_NN);
    u64*   cand = (u64*)  (ws + OFF_CAND);
    float* acc  = (float*)(ws + OFF_ACC);
    u32*   cnt  = (u32*)  (ws + OFF_CNT);
    u32*   bm   = (u32*)  (ws + OFF_BM);
    u32*   kmax = (u32*)  (ws + OFF_KMAX);

    k_init <<<1024, 256, 0, stream>>>((uint4*)gtb, nn, acc, cnt, bm, (uint4*)kmax);
    k_nn   <<<dim3(1024, 2), 256, 0, stream>>>(ref_points, src_points, ref_c, src_c,
                                               rbi, sbi, bm, nn);
    k_msc  <<<32, 256, 0, stream>>>(nn, bm, spm, gti, gtv, gtb, kmax, cand, cnt, acc);
    k_gemm <<<dim3(32, 16), 256, 0, stream>>>(ref_f, src_f, spm, gtb, rowp, colp);
    k_merge<<<64, 256, 0, stream>>>(rowp, colp, acc, cnt, (float*)d_out);
}

// Round 23
// 101.142 us; speedup vs baseline: 1.1127x; 1.0012x over previous
//
#include <hip/hip_runtime.h>
#include <math.h>

using u8  = unsigned char;
using u32 = unsigned int;
using u64 = unsigned long long;

typedef short short8 __attribute__((ext_vector_type(8)));
typedef float f32x4  __attribute__((ext_vector_type(4)));
typedef float f32x2  __attribute__((ext_vector_type(2)));

#define MC 2048
#define NC 2048
#define DF 256
#define NFULL 50000
#define NBACK 30000
#define KCORR 4096
#define MAXPTS 256
#define NN_CHUNK 196   // 256 chunks * 196 = 50176 >= 50000; 49 groups of 4
#define BM_WORDS_I 1568

// ---------------- workspace layout ----------------
constexpr size_t OFF_ROWP = 0;                                // 64*2048 float4 = 2 MB
constexpr size_t OFF_COLP = (size_t)2 * 1024 * 1024;          // 32*2048 float4 = 1 MB
constexpr size_t OFF_GTB  = (size_t)3 * 1024 * 1024;          // 2048*64 u32 = 512 KB (bitfield)
constexpr size_t OFF_NN   = OFF_GTB + (size_t)512 * 1024;     // 4096 u64 = 32 KB
constexpr size_t OFF_CAND = OFF_NN + 4096 * 8;                // 4096 u64 = 32 KB
constexpr size_t OFF_ACC  = OFF_CAND + 4096 * 8;              // 8 f32
constexpr size_t OFF_CNT  = OFF_ACC + 256;                    // counters/tickets
constexpr size_t OFF_BM   = OFF_CNT + 256;                    // 2*1568 u32 = 12.5 KB
constexpr size_t OFF_KMAX = (size_t)4 * 1024 * 1024;          // 4M u32 = 16 MB (per-cell max-k)

// cnt[] map: 0=cand count, 1=merge ticket, 2=mscA ticket, 3=mscB ticket

__device__ __forceinline__ u32 mask_of(const u64* nn, const u32* bm, int idx, int side) {
    u32 j = (u32)(nn[idx] & 0xFFFFFFFFull);
    return (bm[side * BM_WORDS_I + (j >> 5)] >> (j & 31)) & 1u;
}

__device__ __forceinline__ void circle_terms(float d, bool g, float& lp, float& ln) {
    if (g) { float a = d - 0.1f; lp = a > 0.f ? 24.f*a*a : 0.f; ln = 0.f; }
    else   { float b = 1.4f - d; ln = b > 0.f ? 24.f*b*b : 0.f; lp = 0.f; }
}

__device__ __forceinline__ float softplus_(float x) {
    return fmaxf(x, 0.f) + log1pf(expf(-fabsf(x)));
}

// online-LSE merge: (M,S) <- (M,S) + (M2,S2)
__device__ __forceinline__ void lse_merge(float& M, float& S, float M2, float S2) {
    float nm = fmaxf(M, M2);
    S = S * expf(M - nm) + S2 * expf(M2 - nm);
    M = nm;
}

// block-wide ticket barrier
__device__ __forceinline__ void block_barrier(u32* counter, u32 target, u32* s_tic) {
    __threadfence();
    __syncthreads();
    if (threadIdx.x == 0) {
        *s_tic = atomicAdd(counter, 1u);
        while (__hip_atomic_load(counter, __ATOMIC_ACQUIRE, __HIP_MEMORY_SCOPE_AGENT) < target) {}
    }
    __syncthreads();
}

// ---------------- init: zero kmax(16MB)/gtb/nn/bm/acc/cnt ----------------
__global__ __launch_bounds__(256) void k_init(uint4* __restrict__ gtb4, u64* __restrict__ nn,
                                              float* __restrict__ acc, u32* __restrict__ cnt,
                                              u32* __restrict__ bm, uint4* __restrict__ kmax4) {
    int e = blockIdx.x * 256 + threadIdx.x;   // 0..262143
    #pragma unroll
    for (int u = 0; u < 4; ++u)
        kmax4[e + u * 262144] = make_uint4(0u, 0u, 0u, 0u);   // 4M u32
    if (e < 32768) gtb4[e] = make_uint4(0u, 0u, 0u, 0u);
    if (e < 4096) nn[e] = ~0ull;
    if (e < 2 * BM_WORDS_I) bm[e] = 0u;
    if (e < 8) acc[e] = 0.f;
    if (e < 8) cnt[e] = 0u;
}

// ---------------- NN argmin: SoA-by-4 LDS, packed-f32, IPT=2, 8 blocks/CU (R19) ----
__global__ __launch_bounds__(256) void k_nn(
        const float* __restrict__ fr, const float* __restrict__ fs,
        const float* __restrict__ cr, const float* __restrict__ cs,
        const int* __restrict__ rbi, const int* __restrict__ sbi,
        u32* __restrict__ bm, u64* __restrict__ nn) {
    const int side = blockIdx.y;
    const float* full = side ? fs : fr;
    const float* corr = side ? cs : cr;
    const int ib = blockIdx.x & 3, ch = blockIdx.x >> 2;
    const int t = threadIdx.x;

    // folded k_bm: 235*256 = 60160 >= 60000 entries (side-0 blocks only)
    int gb = side * 1024 + blockIdx.x;
    if (gb < 235) {
        int e = gb * 256 + t;
        if (e < 2 * NBACK) {
            int s2 = e < NBACK ? 0 : 1;
            int v = s2 ? sbi[e - NBACK] : rbi[e];
            atomicOr(&bm[s2 * BM_WORDS_I + (v >> 5)], 1u << (v & 31));
        }
    }

    __shared__ float4 sx4[49], sy4[49], sz4[49], sw4[49];
    const int j0 = ch * NN_CHUNK;
    if (t < 49) {
        int b4 = j0 + t * 4;
        float xx[4], yy[4], zz[4], ww[4];
        #pragma unroll
        for (int u = 0; u < 4; ++u) {
            int j = b4 + u;
            if (j < NFULL) {
                float x = full[j*3], y = full[j*3+1], z = full[j*3+2];
                xx[u] = x; yy[u] = y; zz[u] = z;
                ww[u] = fmaf(x, x, fmaf(y, y, z*z));
            } else {
                xx[u] = 0.f; yy[u] = 0.f; zz[u] = 0.f; ww[u] = 3.0e38f;  // sentinel
            }
        }
        sx4[t] = make_float4(xx[0], xx[1], xx[2], xx[3]);
        sy4[t] = make_float4(yy[0], yy[1], yy[2], yy[3]);
        sz4[t] = make_float4(zz[0], zz[1], zz[2], zz[3]);
        sw4[t] = make_float4(ww[0], ww[1], ww[2], ww[3]);
    }

    float ax[2], ay[2], az[2], bd[2];
    int bg[2];
    #pragma unroll
    for (int q = 0; q < 2; ++q) {
        int i = ib * 512 + q * 256 + t;
        float cx = corr[i*3], cy = corr[i*3+1], cz = corr[i*3+2];
        ax[q] = -2.f*cx; ay[q] = -2.f*cy; az[q] = -2.f*cz;
        bd[q] = 3.4e38f; bg[q] = 0;
    }
    __syncthreads();

    #pragma unroll 2
    for (int g = 0; g < 49; ++g) {
        float4 X = sx4[g], Y = sy4[g], Z = sz4[g], W = sw4[g];
        f32x2 xlo = {X.x, X.y}, xhi = {X.z, X.w};
        f32x2 ylo = {Y.x, Y.y}, yhi = {Y.z, Y.w};
        f32x2 zlo = {Z.x, Z.y}, zhi = {Z.z, Z.w};
        f32x2 wlo = {W.x, W.y}, whi = {W.z, W.w};
        #pragma unroll
        for (int q = 0; q < 2; ++q) {
            f32x2 aq = {ax[q], ax[q]}, bq = {ay[q], ay[q]}, cq2 = {az[q], az[q]};
            f32x2 dlo = __builtin_elementwise_fma(aq, xlo,
                          __builtin_elementwise_fma(bq, ylo,
                            __builtin_elementwise_fma(cq2, zlo, wlo)));
            f32x2 dhi = __builtin_elementwise_fma(aq, xhi,
                          __builtin_elementwise_fma(bq, yhi,
                            __builtin_elementwise_fma(cq2, zhi, whi)));
            f32x2 m2 = __builtin_elementwise_min(dlo, dhi);
            float gm = fminf(m2.x, m2.y);
            bool win = gm < bd[q];
            bd[q] = fminf(bd[q], gm);
            bg[q] = win ? g : bg[q];
        }
    }

    #pragma unroll
    for (int q = 0; q < 2; ++q) {
        int gsel = bg[q];
        float4 X = sx4[gsel], Y = sy4[gsel], Z = sz4[gsel], W = sw4[gsel];
        f32x2 xlo = {X.x, X.y}, xhi = {X.z, X.w};
        f32x2 ylo = {Y.x, Y.y}, yhi = {Y.z, Y.w};
        f32x2 zlo = {Z.x, Z.y}, zhi = {Z.z, Z.w};
        f32x2 wlo = {W.x, W.y}, whi = {W.z, W.w};
        f32x2 aq = {ax[q], ax[q]}, bq = {ay[q], ay[q]}, cq2 = {az[q], az[q]};
        f32x2 dlo = __builtin_elementwise_fma(aq, xlo,
                      __builtin_elementwise_fma(bq, ylo,
                        __builtin_elementwise_fma(cq2, zlo, wlo)));
        f32x2 dhi = __builtin_elementwise_fma(aq, xhi,
                      __builtin_elementwise_fma(bq, yhi,
                        __builtin_elementwise_fma(cq2, zhi, whi)));
        float dv[4] = {dlo.x, dlo.y, dhi.x, dhi.y};
        u32 bj = (u32)(j0 + gsel * 4);
        bool found = false;
        #pragma unroll
        for (int u = 0; u < 4; ++u) {
            if (!found && dv[u] == bd[q]) { bj = (u32)(j0 + gsel*4 + u); found = true; }
        }
        int i = ib * 512 + q * 256 + t;
        float cn = 0.25f * fmaf(ax[q], ax[q], fmaf(ay[q], ay[q], az[q]*az[q]));
        float bf = bd[q] + cn;
        u32 db = __float_as_uint(bf);
        db = (db & 0x80000000u) ? ~db : (db | 0x80000000u);
        atomicMin(&nn[side * 2048 + i], ((u64)db << 32) | bj);
    }
}

// ---------------- fused scatter chain: direct-mapped kmax dedup (no hash) ----------
// 32 blocks x 256. R21 lesson: the hash insert's variable-length linear-probe
// chain of cross-XCD atomicCAS (~1us each, worst cluster 20-40 probes) was the
// ~39us cost in every structure since R13. Replaced with ONE fire-and-forget
// atomicMax(kmax[cell], k+1) per entry (no probe chain); winners are
// kmax[cell]==k+1. cell/masked stay in registers between phases.
__global__ __launch_bounds__(256) void k_msc(
        const u64* __restrict__ nn, const u32* __restrict__ bm,
        const float* __restrict__ spm, const int* __restrict__ gti,
        const float* __restrict__ gtv,
        u32* __restrict__ gtb, u32* __restrict__ kmax, u64* __restrict__ cand,
        u32* __restrict__ cnt, float* __restrict__ acc) {
    const int b = blockIdx.x, t = threadIdx.x;
    __shared__ u64 keys[4096];
    __shared__ u32 s_tic;
    __shared__ float red2[4];

    // ---- phase A: loss2 + gtb bit-set + kmax dedup (t<128; e = entry 0..4095) ----
    const int e = b * 128 + t;
    float c = 0.f;
    u32 cell = 0, masked = 0;
    if (t < 128) {
        c = fabsf((1.f - spm[e]) - (float)mask_of(nn, bm, e, e >> 11));
        int xi = gti[2*e], yi = gti[2*e+1];
        cell = (u32)(xi * 2048 + yi);
        masked = mask_of(nn, bm, xi, 0) & mask_of(nn, bm, 2048 + yi, 1);
        if (masked) atomicOr(&gtb[xi * 64 + (yi >> 5)], 1u << (yi & 31));
        atomicMax(&kmax[cell], (u32)e + 1u);   // last-wins = max k per cell
    }
    for (int o = 32; o; o >>= 1) c += __shfl_xor(c, o);
    if ((t & 63) == 0) red2[t >> 6] = c;
    __syncthreads();
    if (t == 0) atomicAdd(&acc[2], red2[0] + red2[1] + red2[2] + red2[3]);

    block_barrier(&cnt[2], 32u, &s_tic);

    // ---- phase B: collect winners (one load, no chain) ----
    if (t < 128) {
        u32 wk = __hip_atomic_load(&kmax[cell], __ATOMIC_RELAXED, __HIP_MEMORY_SCOPE_AGENT);
        if (masked && wk == (u32)e + 1u) {
            u32 vb = __float_as_uint(gtv[e]);   // overlaps >= 0 -> bits monotonic
            u32 idx = atomicAdd(&cnt[0], 1u);
            cand[idx] = ((u64)vb << 22) | (u32)(0x3FFFFF - cell);
        }
    }
    block_barrier(&cnt[3], 32u, &s_tic);

    // ---- phase C: top-256 cap (blocks 0-15) ----
    if (b < 16) {
        const int n = (int)__hip_atomic_load(&cnt[0], __ATOMIC_RELAXED, __HIP_MEMORY_SCOPE_AGENT);
        if (n > MAXPTS && b * 256 < n) {
            for (int e2 = t; e2 < n; e2 += 256)
                keys[e2] = __hip_atomic_load(&cand[e2], __ATOMIC_RELAXED, __HIP_MEMORY_SCOPE_AGENT);
            __syncthreads();
            int c2 = b * 256 + t;
            if (c2 < n) {
                u64 me = keys[c2];
                int rank = 0;
                #pragma unroll 4
                for (int j = 0; j < n; ++j) rank += (keys[j] > me);
                if (rank >= MAXPTS) {
                    u32 cl = 0x3FFFFFu - (u32)(me & 0x3FFFFFull);
                    int row = cl >> 11, col = cl & 2047;
                    atomicAnd(&gtb[row * 64 + (col >> 5)], ~(1u << (col & 31)));
                }
            }
        }
    }
}

// ---------------- fused MFMA bf16 GEMM + laplace + row/col LSE partials (R13) ------
__global__ __launch_bounds__(256) void k_gemm(
        const float* __restrict__ A, const float* __restrict__ B,
        const float* __restrict__ spm, const u32* __restrict__ gtb,
        float4* __restrict__ rowp, float4* __restrict__ colp) {
    __shared__ __align__(16) short As[16384];   // 32 KB
    __shared__ __align__(16) short Bs[8192];    // 16 KB
    __shared__ u32 gtw[256];                    // 1 KB
    const int t = threadIdx.x;
    const int l = t & 63, wid = t >> 6;
    const int wm = wid >> 1, wn = wid & 1;
    const int i0 = blockIdx.y * 128, j0 = blockIdx.x * 64;

    gtw[t] = gtb[(size_t)(i0 + (t >> 1)) * 64 + (j0 >> 5) + (t & 1)];

    f32x4 acc[4][2] = {};

    for (int ks = 0; ks < 2; ++ks) {
        __syncthreads();
        #pragma unroll
        for (int it = 0; it < 12; ++it) {
            int sl = it * 256 + t;                 // 0..3071 slots of 16B
            int c = sl & 63, q = c >> 4, r15 = c & 15;
            const float* src;
            short* dst;
            int kf;
            if (it < 8) {                          // A: slots 0..2047
                int frag = sl >> 6;                // mf(8) x kf(4)
                kf = frag & 3;
                int row = (frag >> 2) * 16 + r15;
                src = A + (size_t)(i0 + row) * 256;
                dst = &As[sl * 8];
            } else {                               // B: slots 2048..3071
                int sl2 = sl - 2048;
                int frag = sl2 >> 6;               // nf(4) x kf(4)
                kf = frag & 3;
                int row = (frag >> 2) * 16 + r15;
                src = B + (size_t)(j0 + row) * 256;
                dst = &Bs[sl2 * 8];
            }
            int col = ks * 128 + kf * 32 + q * 8;
            float4 v0 = *(const float4*)(src + col);
            float4 v1 = *(const float4*)(src + col + 4);
            u32 w0 = __builtin_amdgcn_perm(__float_as_uint(v0.y), __float_as_uint(v0.x), 0x07060302u);
            u32 w1 = __builtin_amdgcn_perm(__float_as_uint(v0.w), __float_as_uint(v0.z), 0x07060302u);
            u32 w2 = __builtin_amdgcn_perm(__float_as_uint(v1.y), __float_as_uint(v1.x), 0x07060302u);
            u32 w3 = __builtin_amdgcn_perm(__float_as_uint(v1.w), __float_as_uint(v1.z), 0x07060302u);
            *(uint4*)dst = make_uint4(w0, w1, w2, w3);
        }
        __syncthreads();

        #pragma unroll
        for (int kf = 0; kf < 4; ++kf) {
            short8 a[4], b[2];
            #pragma unroll
            for (int mi = 0; mi < 4; ++mi)
                a[mi] = *(const short8*)&As[(((wm*4 + mi)*4 + kf) << 9) + l*8];
            #pragma unroll
            for (int ni = 0; ni < 2; ++ni)
                b[ni] = *(const short8*)&Bs[(((wn*2 + ni)*4 + kf) << 9) + l*8];
            #pragma unroll
            for (int mi = 0; mi < 4; ++mi)
                #pragma unroll
                for (int ni = 0; ni < 2; ++ni)
                    acc[mi][ni] = __builtin_amdgcn_mfma_f32_16x16x32_bf16(
                        a[mi], b[ni], acc[mi][ni], 0, 0, 0);
        }
    }

    // epilogue: C/D layout col=lane&15, row=(lane>>4)*4+reg [m89-verified]
    const int cq = l >> 4, cr = l & 15;
    const int rows0 = i0 + wm * 64, cols0 = j0 + wn * 32;

    float vmj[2];
    #pragma unroll
    for (int ni = 0; ni < 2; ++ni) vmj[ni] = 1.f - spm[2048 + cols0 + ni*16 + cr];
    float vmi[4][4];
    #pragma unroll
    for (int mi = 0; mi < 4; ++mi)
        #pragma unroll
        for (int rr = 0; rr < 4; ++rr)
            vmi[mi][rr] = 1.f - spm[rows0 + mi*16 + cq*4 + rr];

    u32 gmask = 0;
    #pragma unroll
    for (int mi = 0; mi < 4; ++mi)
        #pragma unroll
        for (int rr = 0; rr < 4; ++rr) {
            u32 w = gtw[(wm*64 + mi*16 + cq*4 + rr) * 2 + wn];
            #pragma unroll
            for (int ni = 0; ni < 2; ++ni)
                if ((w >> (ni*16 + cr)) & 1u) gmask |= 1u << (mi*8 + ni*4 + rr);
        }
    #pragma unroll
    for (int mi = 0; mi < 4; ++mi)
        #pragma unroll
        for (int ni = 0; ni < 2; ++ni)
            #pragma unroll
            for (int rr = 0; rr < 4; ++rr) {
                float s  = acc[mi][ni][rr];
                float fs = fmaxf(2.f - 2.f*s, 0.f);
                acc[mi][ni][rr] = sqrtf(fs) * expf(0.5f * vmi[mi][rr] * vmj[ni]);
            }

    const int jt2 = blockIdx.x * 2 + wn;   // 0..63
    const int it2 = blockIdx.y * 2 + wm;   // 0..31

    #pragma unroll
    for (int mi = 0; mi < 4; ++mi)
        #pragma unroll
        for (int rr = 0; rr < 4; ++rr) {
            float lp0, ln0, lp1, ln1;
            circle_terms(acc[mi][0][rr], (gmask >> (mi*8 + rr)) & 1, lp0, ln0);
            circle_terms(acc[mi][1][rr], (gmask >> (mi*8 + 4 + rr)) & 1, lp1, ln1);
            float mp = fmaxf(lp0, lp1), mn = fmaxf(ln0, ln1);
            #pragma unroll
            for (int o = 1; o < 16; o <<= 1) {
                mp = fmaxf(mp, __shfl_xor(mp, o));
                mn = fmaxf(mn, __shfl_xor(mn, o));
            }
            float sp = expf(lp0 - mp) + expf(lp1 - mp);
            float sn = expf(ln0 - mn) + expf(ln1 - mn);
            #pragma unroll
            for (int o = 1; o < 16; o <<= 1) {
                sp += __shfl_xor(sp, o);
                sn += __shfl_xor(sn, o);
            }
            if (cr == mi*4 + rr) {
                int row = rows0 + mi*16 + cq*4 + rr;
                rowp[(size_t)jt2 * 2048 + row] = make_float4(mp, sp, mn, sn);
            }
        }

    #pragma unroll
    for (int ni = 0; ni < 2; ++ni) {
        float lp[16], ln[16];
        #pragma unroll
        for (int mi = 0; mi < 4; ++mi)
            #pragma unroll
            for (int rr = 0; rr < 4; ++rr)
                circle_terms(acc[mi][ni][rr], (gmask >> (mi*8 + ni*4 + rr)) & 1,
                             lp[mi*4+rr], ln[mi*4+rr]);
        float mp = lp[0], mn = ln[0];
        #pragma unroll
        for (int e = 1; e < 16; ++e) { mp = fmaxf(mp, lp[e]); mn = fmaxf(mn, ln[e]); }
        #pragma unroll
        for (int o = 16; o < 64; o <<= 1) {
            mp = fmaxf(mp, __shfl_xor(mp, o));
            mn = fmaxf(mn, __shfl_xor(mn, o));
        }
        float sp = 0.f, sn = 0.f;
        #pragma unroll
        for (int e = 0; e < 16; ++e) { sp += expf(lp[e] - mp); sn += expf(ln[e] - mn); }
        #pragma unroll
        for (int o = 16; o < 64; o <<= 1) {
            sp += __shfl_xor(sp, o);
            sn += __shfl_xor(sn, o);
        }
        if (cq == 0) {
            int col = cols0 + ni*16 + cr;
            colp[(size_t)it2 * 2048 + col] = make_float4(mp, sp, mn, sn);
        }
    }
}

// ---------------- merge partials: 64 blocks, 4 threads/element (R18, proven) ------
__global__ __launch_bounds__(256) void k_merge(const float4* __restrict__ rowp,
                                               const float4* __restrict__ colp,
                                               float* __restrict__ acc,
                                               u32* __restrict__ cnt,
                                               float* __restrict__ out) {
    const int t = threadIdx.x;
    const int b = blockIdx.x;    // 0..63
    const int sub = t & 3;
    float Mp = -1e30f, Sp = 0.f, Mn = -1e30f, Sn = 0.f;

    if (b < 32) {
        int row = (b * 256 + t) >> 2;           // 0..2047
        int base = sub * 16;
        #pragma unroll
        for (int j = 0; j < 16; j += 8) {
            float4 pb[8];
            #pragma unroll
            for (int u = 0; u < 8; ++u)
                pb[u] = rowp[(size_t)(base + j + u) * 2048 + row];
            #pragma unroll
            for (int u = 0; u < 8; ++u) {
                lse_merge(Mp, Sp, pb[u].x, pb[u].y);
                lse_merge(Mn, Sn, pb[u].z, pb[u].w);
            }
        }
    } else {
        int col = ((b - 32) * 256 + t) >> 2;    // 0..2047
        int base = sub * 8;
        float4 pb[8];
        #pragma unroll
        for (int u = 0; u < 8; ++u)
            pb[u] = colp[(size_t)(base + u) * 2048 + col];
        #pragma unroll
        for (int u = 0; u < 8; ++u) {
            lse_merge(Mp, Sp, pb[u].x, pb[u].y);
            lse_merge(Mn, Sn, pb[u].z, pb[u].w);
        }
    }

    #pragma unroll
    for (int o = 1; o < 4; o <<= 1) {
        float M2 = __shfl_xor(Mp, o), S2 = __shfl_xor(Sp, o);
        lse_merge(Mp, Sp, M2, S2);
        M2 = __shfl_xor(Mn, o); S2 = __shfl_xor(Sn, o);
        lse_merge(Mn, Sn, M2, S2);
    }

    float lv = 0.f;
    if (sub == 0) {
        float x = (Mp + logf(Sp)) + (Mn + logf(Sn));
        lv = softplus_(x) * (1.f / 24.f);
    }
    for (int o = 32; o; o >>= 1) lv += __shfl_xor(lv, o);
    __shared__ float wsum[4];
    __shared__ u32 tic;
    if ((t & 63) == 0) wsum[t >> 6] = lv;
    __syncthreads();
    if (t == 0) {
        atomicAdd(&acc[b < 32 ? 0 : 1], wsum[0] + wsum[1] + wsum[2] + wsum[3]);
        __threadfence();
        tic = atomicAdd(&cnt[1], 1u);
    }
    __syncthreads();
    if (t == 0 && tic == 63u) {
        __threadfence();
        float a0 = atomicAdd(&acc[0], 0.f);
        float a1 = atomicAdd(&acc[1], 0.f);
        float a2 = atomicAdd(&acc[2], 0.f);
        float l1 = (a0 + a1) * (0.5f / 2048.f);
        float l2 = a2 * (1.f / 4096.f);
        out[0] = l1 + l2; out[1] = l1; out[2] = l2;
    }
}

extern "C" void kernel_launch(void* const* d_in, const int* in_sizes, int n_in,
                              void* d_out, int out_size, void* d_ws, size_t ws_size,
                              hipStream_t stream) {
    (void)in_sizes; (void)n_in; (void)out_size; (void)ws_size;
    const float* ref_points = (const float*)d_in[0];
    const float* src_points = (const float*)d_in[1];
    const float* ref_c      = (const float*)d_in[2];
    const float* src_c      = (const float*)d_in[3];
    const float* ref_f      = (const float*)d_in[4];
    const float* src_f      = (const float*)d_in[5];
    const int*   gti        = (const int*)d_in[6];
    const float* gtv        = (const float*)d_in[7];
    const float* spm        = (const float*)d_in[8];
    const int*   rbi        = (const int*)d_in[9];
    const int*   sbi        = (const int*)d_in[10];

    char* ws = (char*)d_ws;
    float4* rowp = (float4*)(ws + OFF_ROWP);
    float4* colp = (float4*)(ws + OFF_COLP);
    u32*   gtb  = (u32*)  (ws + OFF_GTB);
    u64*   nn   = (u64*)  (ws + OFF_NN);
    u64*   cand = (u64*)  (ws + OFF_CAND);
    float* acc  = (float*)(ws + OFF_ACC);
    u32*   cnt  = (u32*)  (ws + OFF_CNT);
    u32*   bm   = (u32*)  (ws + OFF_BM);
    u32*   kmax = (u32*)  (ws + OFF_KMAX);

    k_init <<<1024, 256, 0, stream>>>((uint4*)gtb, nn, acc, cnt, bm, (uint4*)kmax);
    k_nn   <<<dim3(1024, 2), 256, 0, stream>>>(ref_points, src_points, ref_c, src_c,
                                               rbi, sbi, bm, nn);
    k_msc  <<<32, 256, 0, stream>>>(nn, bm, spm, gti, gtv, gtb, kmax, cand, cnt, acc);
    k_gemm <<<dim3(32, 16), 256, 0, stream>>>(ref_f, src_f, spm, gtb, rowp, colp);
    k_merge<<<64, 256, 0, stream>>>(rowp, colp, acc, cnt, (float*)d_out);
}

// Round 24
// 95.570 us; speedup vs baseline: 1.1776x; 1.0583x over previous
//
#include <hip/hip_runtime.h>
#include <math.h>

using u8  = unsigned char;
using u32 = unsigned int;
using u64 = unsigned long long;

typedef short short8 __attribute__((ext_vector_type(8)));
typedef float f32x4  __attribute__((ext_vector_type(4)));
typedef float f32x2  __attribute__((ext_vector_type(2)));

#define MC 2048
#define NC 2048
#define DF 256
#define NFULL 50000
#define NBACK 30000
#define KCORR 4096
#define MAXPTS 256
#define NN_CHUNK 196   // 256 chunks * 196 = 50176 >= 50000; 49 groups of 4
#define BM_WORDS_I 1568

// ---------------- workspace layout ----------------
constexpr size_t OFF_ROWP = 0;                                // 64*2048 float4 = 2 MB
constexpr size_t OFF_COLP = (size_t)2 * 1024 * 1024;          // 32*2048 float4 = 1 MB
constexpr size_t OFF_GTB  = (size_t)3 * 1024 * 1024;          // 2048*64 u32 = 512 KB (bitfield)
constexpr size_t OFF_NN   = OFF_GTB + (size_t)512 * 1024;     // 4096 u64 = 32 KB
constexpr size_t OFF_CAND = OFF_NN + 4096 * 8;                // 4096 u64 = 32 KB
constexpr size_t OFF_MC   = OFF_CAND + 4096 * 8;              // 4096 u32 = 16 KB (cell|masked)
constexpr size_t OFF_ACC  = OFF_MC + 4096 * 4;                // 8 f32
constexpr size_t OFF_CNT  = OFF_ACC + 256;                    // counters/tickets
constexpr size_t OFF_BM   = OFF_CNT + 256;                    // 2*1568 u32 = 12.5 KB
constexpr size_t OFF_KMAX = (size_t)4 * 1024 * 1024;          // 4M u32 = 16 MB (per-cell max-k; only touched cells zeroed)

// cnt[] map: 0=cand count, 1=merge ticket

__device__ __forceinline__ u32 mask_of(const u64* nn, const u32* bm, int idx, int side) {
    u32 j = (u32)(nn[idx] & 0xFFFFFFFFull);
    return (bm[side * BM_WORDS_I + (j >> 5)] >> (j & 31)) & 1u;
}

__device__ __forceinline__ void circle_terms(float d, bool g, float& lp, float& ln) {
    if (g) { float a = d - 0.1f; lp = a > 0.f ? 24.f*a*a : 0.f; ln = 0.f; }
    else   { float b = 1.4f - d; ln = b > 0.f ? 24.f*b*b : 0.f; lp = 0.f; }
}

__device__ __forceinline__ float softplus_(float x) {
    return fmaxf(x, 0.f) + log1pf(expf(-fabsf(x)));
}

// online-LSE merge: (M,S) <- (M,S) + (M2,S2)
__device__ __forceinline__ void lse_merge(float& M, float& S, float M2, float S2) {
    float nm = fmaxf(M, M2);
    S = S * expf(M - nm) + S2 * expf(M2 - nm);
    M = nm;
}

// ---------------- init: zero gtb/nn/bm/acc/cnt + touched kmax cells only ----------
__global__ __launch_bounds__(256) void k_init(uint4* __restrict__ gtb4, u64* __restrict__ nn,
                                              float* __restrict__ acc, u32* __restrict__ cnt,
                                              u32* __restrict__ bm, u32* __restrict__ kmax,
                                              const int* __restrict__ gti) {
    int e = blockIdx.x * 256 + threadIdx.x;   // 0..32767
    gtb4[e] = make_uint4(0u, 0u, 0u, 0u);
    if (e < 4096) {
        nn[e] = ~0ull;
        // zero only the kmax cells this call will touch (R23 lesson: 16MB blanket
        // zero cost ~2.5us; scattered 4096-cell zero is ~free)
        int xi = gti[2*e], yi = gti[2*e+1];
        kmax[xi * 2048 + yi] = 0u;
    }
    if (e < 2 * BM_WORDS_I) bm[e] = 0u;
    if (e < 8) acc[e] = 0.f;
    if (e < 8) cnt[e] = 0u;
}

// ---------------- NN argmin: SoA-by-4 LDS, packed-f32, IPT=2, 8 blocks/CU (R19) ----
__global__ __launch_bounds__(256) void k_nn(
        const float* __restrict__ fr, const float* __restrict__ fs,
        const float* __restrict__ cr, const float* __restrict__ cs,
        const int* __restrict__ rbi, const int* __restrict__ sbi,
        u32* __restrict__ bm, u64* __restrict__ nn) {
    const int side = blockIdx.y;
    const float* full = side ? fs : fr;
    const float* corr = side ? cs : cr;
    const int ib = blockIdx.x & 3, ch = blockIdx.x >> 2;
    const int t = threadIdx.x;

    // folded k_bm: 235*256 = 60160 >= 60000 entries (side-0 blocks only)
    int gb = side * 1024 + blockIdx.x;
    if (gb < 235) {
        int e = gb * 256 + t;
        if (e < 2 * NBACK) {
            int s2 = e < NBACK ? 0 : 1;
            int v = s2 ? sbi[e - NBACK] : rbi[e];
            atomicOr(&bm[s2 * BM_WORDS_I + (v >> 5)], 1u << (v & 31));
        }
    }

    __shared__ float4 sx4[49], sy4[49], sz4[49], sw4[49];
    const int j0 = ch * NN_CHUNK;
    if (t < 49) {
        int b4 = j0 + t * 4;
        float xx[4], yy[4], zz[4], ww[4];
        #pragma unroll
        for (int u = 0; u < 4; ++u) {
            int j = b4 + u;
            if (j < NFULL) {
                float x = full[j*3], y = full[j*3+1], z = full[j*3+2];
                xx[u] = x; yy[u] = y; zz[u] = z;
                ww[u] = fmaf(x, x, fmaf(y, y, z*z));
            } else {
                xx[u] = 0.f; yy[u] = 0.f; zz[u] = 0.f; ww[u] = 3.0e38f;  // sentinel
            }
        }
        sx4[t] = make_float4(xx[0], xx[1], xx[2], xx[3]);
        sy4[t] = make_float4(yy[0], yy[1], yy[2], yy[3]);
        sz4[t] = make_float4(zz[0], zz[1], zz[2], zz[3]);
        sw4[t] = make_float4(ww[0], ww[1], ww[2], ww[3]);
    }

    float ax[2], ay[2], az[2], bd[2];
    int bg[2];
    #pragma unroll
    for (int q = 0; q < 2; ++q) {
        int i = ib * 512 + q * 256 + t;
        float cx = corr[i*3], cy = corr[i*3+1], cz = corr[i*3+2];
        ax[q] = -2.f*cx; ay[q] = -2.f*cy; az[q] = -2.f*cz;
        bd[q] = 3.4e38f; bg[q] = 0;
    }
    __syncthreads();

    #pragma unroll 2
    for (int g = 0; g < 49; ++g) {
        float4 X = sx4[g], Y = sy4[g], Z = sz4[g], W = sw4[g];
        f32x2 xlo = {X.x, X.y}, xhi = {X.z, X.w};
        f32x2 ylo = {Y.x, Y.y}, yhi = {Y.z, Y.w};
        f32x2 zlo = {Z.x, Z.y}, zhi = {Z.z, Z.w};
        f32x2 wlo = {W.x, W.y}, whi = {W.z, W.w};
        #pragma unroll
        for (int q = 0; q < 2; ++q) {
            f32x2 aq = {ax[q], ax[q]}, bq = {ay[q], ay[q]}, cq2 = {az[q], az[q]};
            f32x2 dlo = __builtin_elementwise_fma(aq, xlo,
                          __builtin_elementwise_fma(bq, ylo,
                            __builtin_elementwise_fma(cq2, zlo, wlo)));
            f32x2 dhi = __builtin_elementwise_fma(aq, xhi,
                          __builtin_elementwise_fma(bq, yhi,
                            __builtin_elementwise_fma(cq2, zhi, whi)));
            f32x2 m2 = __builtin_elementwise_min(dlo, dhi);
            float gm = fminf(m2.x, m2.y);
            bool win = gm < bd[q];
            bd[q] = fminf(bd[q], gm);
            bg[q] = win ? g : bg[q];
        }
    }

    #pragma unroll
    for (int q = 0; q < 2; ++q) {
        int gsel = bg[q];
        float4 X = sx4[gsel], Y = sy4[gsel], Z = sz4[gsel], W = sw4[gsel];
        f32x2 xlo = {X.x, X.y}, xhi = {X.z, X.w};
        f32x2 ylo = {Y.x, Y.y}, yhi = {Y.z, Y.w};
        f32x2 zlo = {Z.x, Z.y}, zhi = {Z.z, Z.w};
        f32x2 wlo = {W.x, W.y}, whi = {W.z, W.w};
        f32x2 aq = {ax[q], ax[q]}, bq = {ay[q], ay[q]}, cq2 = {az[q], az[q]};
        f32x2 dlo = __builtin_elementwise_fma(aq, xlo,
                      __builtin_elementwise_fma(bq, ylo,
                        __builtin_elementwise_fma(cq2, zlo, wlo)));
        f32x2 dhi = __builtin_elementwise_fma(aq, xhi,
                      __builtin_elementwise_fma(bq, yhi,
                        __builtin_elementwise_fma(cq2, zhi, whi)));
        float dv[4] = {dlo.x, dlo.y, dhi.x, dhi.y};
        u32 bj = (u32)(j0 + gsel * 4);
        bool found = false;
        #pragma unroll
        for (int u = 0; u < 4; ++u) {
            if (!found && dv[u] == bd[q]) { bj = (u32)(j0 + gsel*4 + u); found = true; }
        }
        int i = ib * 512 + q * 256 + t;
        float cn = 0.25f * fmaf(ax[q], ax[q], fmaf(ay[q], ay[q], az[q]*az[q]));
        float bf = bd[q] + cn;
        u32 db = __float_as_uint(bf);
        db = (db & 0x80000000u) ? ~db : (db | 0x80000000u);
        atomicMin(&nn[side * 2048 + i], ((u64)db << 32) | bj);
    }
}

// ---------------- msc: loss2 + gtb-set + kmax dedup (NO barriers/fences) ----------
// 16 blocks x 256, one entry per thread. R23 lesson: the remaining ~25us in the
// fused k_msc is attributed to spin-barrier + threadfence pairs (fence drains
// cross-XCD atomics; spin polls a remote counter at ~1us/poll). Kernel
// boundaries provide the same ordering for ~free (R19 measurement).
__global__ __launch_bounds__(256) void k_msc(
        const u64* __restrict__ nn, const u32* __restrict__ bm,
        const float* __restrict__ spm, const int* __restrict__ gti,
        u32* __restrict__ gtb, u32* __restrict__ kmax, u32* __restrict__ mcell,
        float* __restrict__ acc) {
    const int b = blockIdx.x, t = threadIdx.x;
    const int e = b * 256 + t;   // 0..4095
    __shared__ float red2[4];

    float c = fabsf((1.f - spm[e]) - (float)mask_of(nn, bm, e, e >> 11));
    int xi = gti[2*e], yi = gti[2*e+1];
    u32 cell = (u32)(xi * 2048 + yi);
    u32 masked = mask_of(nn, bm, xi, 0) & mask_of(nn, bm, 2048 + yi, 1);
    if (masked) atomicOr(&gtb[xi * 64 + (yi >> 5)], 1u << (yi & 31));
    atomicMax(&kmax[cell], (u32)e + 1u);        // last-wins = max k per cell
    mcell[e] = cell | (masked << 31);           // cache for k_scat2

    for (int o = 32; o; o >>= 1) c += __shfl_xor(c, o);
    if ((t & 63) == 0) red2[t >> 6] = c;
    __syncthreads();
    if (t == 0) atomicAdd(&acc[2], red2[0] + red2[1] + red2[2] + red2[3]);
}

// ---------------- scat2: collect winners (one kmax load each) ----------------
__global__ __launch_bounds__(256) void k_scat2(
        const u32* __restrict__ kmax, const u32* __restrict__ mcell,
        const float* __restrict__ gtv, u64* __restrict__ cand, u32* __restrict__ cnt) {
    const int e = blockIdx.x * 256 + threadIdx.x;   // 0..4095
    u32 mc = mcell[e];
    if (!(mc >> 31)) return;                        // not masked
    u32 cell = mc & 0x3FFFFFu;
    if (kmax[cell] != (u32)e + 1u) return;          // not last-wins winner
    u32 vb = __float_as_uint(gtv[e]);               // overlaps >= 0 -> bits monotonic
    u32 idx = atomicAdd(&cnt[0], 1u);
    cand[idx] = ((u64)vb << 22) | (u32)(0x3FFFFF - cell);
}

// ---------------- top-256 cap, spread over 16 blocks ----------------
__global__ __launch_bounds__(256) void k_top(const u64* __restrict__ cand,
                                             const u32* __restrict__ cnt,
                                             u32* __restrict__ gtb) {
    const int n = (int)cnt[0];
    if (n <= MAXPTS) return;
    if (blockIdx.x * 256 >= n) return;
    __shared__ u64 keys[4096];
    const int t = threadIdx.x;
    for (int e = t; e < n; e += 256) keys[e] = cand[e];
    __syncthreads();
    int c = blockIdx.x * 256 + t;
    if (c >= n) return;
    u64 me = keys[c];
    int rank = 0;
    #pragma unroll 4
    for (int j = 0; j < n; ++j) rank += (keys[j] > me);
    if (rank >= MAXPTS) {
        u32 cell = 0x3FFFFFu - (u32)(me & 0x3FFFFFull);
        int row = cell >> 11, col = cell & 2047;
        atomicAnd(&gtb[row * 64 + (col >> 5)], ~(1u << (col & 31)));
    }
}

// ---------------- fused MFMA bf16 GEMM + laplace + row/col LSE partials (R13) ------
__global__ __launch_bounds__(256) void k_gemm(
        const float* __restrict__ A, const float* __restrict__ B,
        const float* __restrict__ spm, const u32* __restrict__ gtb,
        float4* __restrict__ rowp, float4* __restrict__ colp) {
    __shared__ __align__(16) short As[16384];   // 32 KB
    __shared__ __align__(16) short Bs[8192];    // 16 KB
    __shared__ u32 gtw[256];                    // 1 KB
    const int t = threadIdx.x;
    const int l = t & 63, wid = t >> 6;
    const int wm = wid >> 1, wn = wid & 1;
    const int i0 = blockIdx.y * 128, j0 = blockIdx.x * 64;

    gtw[t] = gtb[(size_t)(i0 + (t >> 1)) * 64 + (j0 >> 5) + (t & 1)];

    f32x4 acc[4][2] = {};

    for (int ks = 0; ks < 2; ++ks) {
        __syncthreads();
        #pragma unroll
        for (int it = 0; it < 12; ++it) {
            int sl = it * 256 + t;                 // 0..3071 slots of 16B
            int c = sl & 63, q = c >> 4, r15 = c & 15;
            const float* src;
            short* dst;
            int kf;
            if (it < 8) {                          // A: slots 0..2047
                int frag = sl >> 6;                // mf(8) x kf(4)
                kf = frag & 3;
                int row = (frag >> 2) * 16 + r15;
                src = A + (size_t)(i0 + row) * 256;
                dst = &As[sl * 8];
            } else {                               // B: slots 2048..3071
                int sl2 = sl - 2048;
                int frag = sl2 >> 6;               // nf(4) x kf(4)
                kf = frag & 3;
                int row = (frag >> 2) * 16 + r15;
                src = B + (size_t)(j0 + row) * 256;
                dst = &Bs[sl2 * 8];
            }
            int col = ks * 128 + kf * 32 + q * 8;
            float4 v0 = *(const float4*)(src + col);
            float4 v1 = *(const float4*)(src + col + 4);
            u32 w0 = __builtin_amdgcn_perm(__float_as_uint(v0.y), __float_as_uint(v0.x), 0x07060302u);
            u32 w1 = __builtin_amdgcn_perm(__float_as_uint(v0.w), __float_as_uint(v0.z), 0x07060302u);
            u32 w2 = __builtin_amdgcn_perm(__float_as_uint(v1.y), __float_as_uint(v1.x), 0x07060302u);
            u32 w3 = __builtin_amdgcn_perm(__float_as_uint(v1.w), __float_as_uint(v1.z), 0x07060302u);
            *(uint4*)dst = make_uint4(w0, w1, w2, w3);
        }
        __syncthreads();

        #pragma unroll
        for (int kf = 0; kf < 4; ++kf) {
            short8 a[4], b[2];
            #pragma unroll
            for (int mi = 0; mi < 4; ++mi)
                a[mi] = *(const short8*)&As[(((wm*4 + mi)*4 + kf) << 9) + l*8];
            #pragma unroll
            for (int ni = 0; ni < 2; ++ni)
                b[ni] = *(const short8*)&Bs[(((wn*2 + ni)*4 + kf) << 9) + l*8];
            #pragma unroll
            for (int mi = 0; mi < 4; ++mi)
                #pragma unroll
                for (int ni = 0; ni < 2; ++ni)
                    acc[mi][ni] = __builtin_amdgcn_mfma_f32_16x16x32_bf16(
                        a[mi], b[ni], acc[mi][ni], 0, 0, 0);
        }
    }

    // epilogue: C/D layout col=lane&15, row=(lane>>4)*4+reg [m89-verified]
    const int cq = l >> 4, cr = l & 15;
    const int rows0 = i0 + wm * 64, cols0 = j0 + wn * 32;

    float vmj[2];
    #pragma unroll
    for (int ni = 0; ni < 2; ++ni) vmj[ni] = 1.f - spm[2048 + cols0 + ni*16 + cr];
    float vmi[4][4];
    #pragma unroll
    for (int mi = 0; mi < 4; ++mi)
        #pragma unroll
        for (int rr = 0; rr < 4; ++rr)
            vmi[mi][rr] = 1.f - spm[rows0 + mi*16 + cq*4 + rr];

    u32 gmask = 0;
    #pragma unroll
    for (int mi = 0; mi < 4; ++mi)
        #pragma unroll
        for (int rr = 0; rr < 4; ++rr) {
            u32 w = gtw[(wm*64 + mi*16 + cq*4 + rr) * 2 + wn];
            #pragma unroll
            for (int ni = 0; ni < 2; ++ni)
                if ((w >> (ni*16 + cr)) & 1u) gmask |= 1u << (mi*8 + ni*4 + rr);
        }
    #pragma unroll
    for (int mi = 0; mi < 4; ++mi)
        #pragma unroll
        for (int ni = 0; ni < 2; ++ni)
            #pragma unroll
            for (int rr = 0; rr < 4; ++rr) {
                float s  = acc[mi][ni][rr];
                float fs = fmaxf(2.f - 2.f*s, 0.f);
                acc[mi][ni][rr] = sqrtf(fs) * expf(0.5f * vmi[mi][rr] * vmj[ni]);
            }

    const int jt2 = blockIdx.x * 2 + wn;   // 0..63
    const int it2 = blockIdx.y * 2 + wm;   // 0..31

    #pragma unroll
    for (int mi = 0; mi < 4; ++mi)
        #pragma unroll
        for (int rr = 0; rr < 4; ++rr) {
            float lp0, ln0, lp1, ln1;
            circle_terms(acc[mi][0][rr], (gmask >> (mi*8 + rr)) & 1, lp0, ln0);
            circle_terms(acc[mi][1][rr], (gmask >> (mi*8 + 4 + rr)) & 1, lp1, ln1);
            float mp = fmaxf(lp0, lp1), mn = fmaxf(ln0, ln1);
            #pragma unroll
            for (int o = 1; o < 16; o <<= 1) {
                mp = fmaxf(mp, __shfl_xor(mp, o));
                mn = fmaxf(mn, __shfl_xor(mn, o));
            }
            float sp = expf(lp0 - mp) + expf(lp1 - mp);
            float sn = expf(ln0 - mn) + expf(ln1 - mn);
            #pragma unroll
            for (int o = 1; o < 16; o <<= 1) {
                sp += __shfl_xor(sp, o);
                sn += __shfl_xor(sn, o);
            }
            if (cr == mi*4 + rr) {
                int row = rows0 + mi*16 + cq*4 + rr;
                rowp[(size_t)jt2 * 2048 + row] = make_float4(mp, sp, mn, sn);
            }
        }

    #pragma unroll
    for (int ni = 0; ni < 2; ++ni) {
        float lp[16], ln[16];
        #pragma unroll
        for (int mi = 0; mi < 4; ++mi)
            #pragma unroll
            for (int rr = 0; rr < 4; ++rr)
                circle_terms(acc[mi][ni][rr], (gmask >> (mi*8 + ni*4 + rr)) & 1,
                             lp[mi*4+rr], ln[mi*4+rr]);
        float mp = lp[0], mn = ln[0];
        #pragma unroll
        for (int e = 1; e < 16; ++e) { mp = fmaxf(mp, lp[e]); mn = fmaxf(mn, ln[e]); }
        #pragma unroll
        for (int o = 16; o < 64; o <<= 1) {
            mp = fmaxf(mp, __shfl_xor(mp, o));
            mn = fmaxf(mn, __shfl_xor(mn, o));
        }
        float sp = 0.f, sn = 0.f;
        #pragma unroll
        for (int e = 0; e < 16; ++e) { sp += expf(lp[e] - mp); sn += expf(ln[e] - mn); }
        #pragma unroll
        for (int o = 16; o < 64; o <<= 1) {
            sp += __shfl_xor(sp, o);
            sn += __shfl_xor(sn, o);
        }
        if (cq == 0) {
            int col = cols0 + ni*16 + cr;
            colp[(size_t)it2 * 2048 + col] = make_float4(mp, sp, mn, sn);
        }
    }
}

// ---------------- merge partials: 64 blocks, 4 threads/element (R18, proven) ------
__global__ __launch_bounds__(256) void k_merge(const float4* __restrict__ rowp,
                                               const float4* __restrict__ colp,
                                               float* __restrict__ acc,
                                               u32* __restrict__ cnt,
                                               float* __restrict__ out) {
    const int t = threadIdx.x;
    const int b = blockIdx.x;    // 0..63
    const int sub = t & 3;
    float Mp = -1e30f, Sp = 0.f, Mn = -1e30f, Sn = 0.f;

    if (b < 32) {
        int row = (b * 256 + t) >> 2;           // 0..2047
        int base = sub * 16;
        #pragma unroll
        for (int j = 0; j < 16; j += 8) {
            float4 pb[8];
            #pragma unroll
            for (int u = 0; u < 8; ++u)
                pb[u] = rowp[(size_t)(base + j + u) * 2048 + row];
            #pragma unroll
            for (int u = 0; u < 8; ++u) {
                lse_merge(Mp, Sp, pb[u].x, pb[u].y);
                lse_merge(Mn, Sn, pb[u].z, pb[u].w);
            }
        }
    } else {
        int col = ((b - 32) * 256 + t) >> 2;    // 0..2047
        int base = sub * 8;
        float4 pb[8];
        #pragma unroll
        for (int u = 0; u < 8; ++u)
            pb[u] = colp[(size_t)(base + u) * 2048 + col];
        #pragma unroll
        for (int u = 0; u < 8; ++u) {
            lse_merge(Mp, Sp, pb[u].x, pb[u].y);
            lse_merge(Mn, Sn, pb[u].z, pb[u].w);
        }
    }

    #pragma unroll
    for (int o = 1; o < 4; o <<= 1) {
        float M2 = __shfl_xor(Mp, o), S2 = __shfl_xor(Sp, o);
        lse_merge(Mp, Sp, M2, S2);
        M2 = __shfl_xor(Mn, o); S2 = __shfl_xor(Sn, o);
        lse_merge(Mn, Sn, M2, S2);
    }

    float lv = 0.f;
    if (sub == 0) {
        float x = (Mp + logf(Sp)) + (Mn + logf(Sn));
        lv = softplus_(x) * (1.f / 24.f);
    }
    for (int o = 32; o; o >>= 1) lv += __shfl_xor(lv, o);
    __shared__ float wsum[4];
    __shared__ u32 tic;
    if ((t & 63) == 0) wsum[t >> 6] = lv;
    __syncthreads();
    if (t == 0) {
        atomicAdd(&acc[b < 32 ? 0 : 1], wsum[0] + wsum[1] + wsum[2] + wsum[3]);
        __threadfence();
        tic = atomicAdd(&cnt[1], 1u);
    }
    __syncthreads();
    if (t == 0 && tic == 63u) {
        __threadfence();
        float a0 = atomicAdd(&acc[0], 0.f);
        float a1 = atomicAdd(&acc[1], 0.f);
        float a2 = atomicAdd(&acc[2], 0.f);
        float l1 = (a0 + a1) * (0.5f / 2048.f);
        float l2 = a2 * (1.f / 4096.f);
        out[0] = l1 + l2; out[1] = l1; out[2] = l2;
    }
}

extern "C" void kernel_launch(void* const* d_in, const int* in_sizes, int n_in,
                              void* d_out, int out_size, void* d_ws, size_t ws_size,
                              hipStream_t stream) {
    (void)in_sizes; (void)n_in; (void)out_size; (void)ws_size;
    const float* ref_points = (const float*)d_in[0];
    const float* src_points = (const float*)d_in[1];
    const float* ref_c      = (const float*)d_in[2];
    const float* src_c      = (const float*)d_in[3];
    const float* ref_f      = (const float*)d_in[4];
    const float* src_f      = (const float*)d_in[5];
    const int*   gti        = (const int*)d_in[6];
    const float* gtv        = (const float*)d_in[7];
    const float* spm        = (const float*)d_in[8];
    const int*   rbi        = (const int*)d_in[9];
    const int*   sbi        = (const int*)d_in[10];

    char* ws = (char*)d_ws;
    float4* rowp = (float4*)(ws + OFF_ROWP);
    float4* colp = (float4*)(ws + OFF_COLP);
    u32*   gtb  = (u32*)  (ws + OFF_GTB);
    u64*   nn   = (u64*)  (ws + OFF_NN);
    u64*   cand = (u64*)  (ws + OFF_CAND);
    u32*   mcell= (u32*)  (ws + OFF_MC);
    float* acc  = (float*)(ws + OFF_ACC);
    u32*   cnt  = (u32*)  (ws + OFF_CNT);
    u32*   bm   = (u32*)  (ws + OFF_BM);
    u32*   kmax = (u32*)  (ws + OFF_KMAX);

    k_init <<<128, 256, 0, stream>>>((uint4*)gtb, nn, acc, cnt, bm, kmax, gti);
    k_nn   <<<dim3(1024, 2), 256, 0, stream>>>(ref_points, src_points, ref_c, src_c,
                                               rbi, sbi, bm, nn);
    k_msc  <<<16, 256, 0, stream>>>(nn, bm, spm, gti, gtb, kmax, mcell, acc);
    k_scat2<<<16, 256, 0, stream>>>(kmax, mcell, gtv, cand, cnt);
    k_top  <<<16, 256, 0, stream>>>(cand, cnt, gtb);
    k_gemm <<<dim3(32, 16), 256, 0, stream>>>(ref_f, src_f, spm, gtb, rowp, colp);
    k_merge<<<64, 256, 0, stream>>>(rowp, colp, acc, cnt, (float*)d_out);
}

// Round 25
// 95.316 us; speedup vs baseline: 1.1807x; 1.0027x over previous
//
#include <hip/hip_runtime.h>
#include <math.h>

using u8  = unsigned char;
using u32 = unsigned int;
using u64 = unsigned long long;

typedef short short8 __attribute__((ext_vector_type(8)));
typedef float f32x4  __attribute__((ext_vector_type(4)));
typedef float f32x2  __attribute__((ext_vector_type(2)));

#define MC 2048
#define NC 2048
#define DF 256
#define NFULL 50000
#define NBACK 30000
#define KCORR 4096
#define MAXPTS 256
#define NN_CHUNK 196   // 256 chunks * 196 = 50176 >= 50000; 49 groups of 4
#define BM_WORDS_I 1568

// ---------------- workspace layout ----------------
constexpr size_t OFF_ROWP = 0;                                // 64*2048 float4 = 2 MB
constexpr size_t OFF_COLP = (size_t)2 * 1024 * 1024;          // 32*2048 float4 = 1 MB
constexpr size_t OFF_GTB  = (size_t)3 * 1024 * 1024;          // 2048*64 u32 = 512 KB (bitfield)
constexpr size_t OFF_NN   = OFF_GTB + (size_t)512 * 1024;     // 4096 u64 = 32 KB
constexpr size_t OFF_CAND = OFF_NN + 4096 * 8;                // 4096 u64 = 32 KB
constexpr size_t OFF_ACC  = OFF_CAND + 4096 * 8;              // 8 f32
constexpr size_t OFF_CNT  = OFF_ACC + 256;                    // counters/tickets
constexpr size_t OFF_BM   = OFF_CNT + 256;                    // 2*1568 u32 = 12.5 KB
constexpr size_t OFF_KMAX = (size_t)4 * 1024 * 1024;          // 4M u32 (touched cells only)

// cnt[] map: 0=cand count, 1=merge ticket

__device__ __forceinline__ u32 mask_of(const u64* nn, const u32* bm, int idx, int side) {
    u32 j = (u32)(nn[idx] & 0xFFFFFFFFull);
    return (bm[side * BM_WORDS_I + (j >> 5)] >> (j & 31)) & 1u;
}

__device__ __forceinline__ void circle_terms(float d, bool g, float& lp, float& ln) {
    if (g) { float a = d - 0.1f; lp = a > 0.f ? 24.f*a*a : 0.f; ln = 0.f; }
    else   { float b = 1.4f - d; ln = b > 0.f ? 24.f*b*b : 0.f; lp = 0.f; }
}

__device__ __forceinline__ float softplus_(float x) {
    return fmaxf(x, 0.f) + log1pf(expf(-fabsf(x)));
}

// online-LSE merge: (M,S) <- (M,S) + (M2,S2)
__device__ __forceinline__ void lse_merge(float& M, float& S, float M2, float S2) {
    float nm = fmaxf(M, M2);
    S = S * expf(M - nm) + S2 * expf(M2 - nm);
    M = nm;
}

// ---------------- init: zero gtb/nn/bm/acc/cnt + touched kmax cells only ----------
__global__ __launch_bounds__(256) void k_init(uint4* __restrict__ gtb4, u64* __restrict__ nn,
                                              float* __restrict__ acc, u32* __restrict__ cnt,
                                              u32* __restrict__ bm, u32* __restrict__ kmax,
                                              const int* __restrict__ gti) {
    int e = blockIdx.x * 256 + threadIdx.x;   // 0..32767
    gtb4[e] = make_uint4(0u, 0u, 0u, 0u);
    if (e < 4096) {
        nn[e] = ~0ull;
        int xi = gti[2*e], yi = gti[2*e+1];
        kmax[xi * 2048 + yi] = 0u;            // zero only touched cells
    }
    if (e < 2 * BM_WORDS_I) bm[e] = 0u;
    if (e < 8) acc[e] = 0.f;
    if (e < 8) cnt[e] = 0u;
}

// ---------------- NN argmin + bm build (side-0 blocks) + kmax insert (side-1) ------
// R24 lesson: launch boundaries cost ~7us each; the kmax dedup INSERT depends
// only on gti + zeroed kmax, so it rides in k_nn's prologue (16 side-1 blocks),
// using the existing init->nn->msc boundaries for ordering. k_scat2 deleted.
__global__ __launch_bounds__(256) void k_nn(
        const float* __restrict__ fr, const float* __restrict__ fs,
        const float* __restrict__ cr, const float* __restrict__ cs,
        const int* __restrict__ rbi, const int* __restrict__ sbi,
        const int* __restrict__ gti,
        u32* __restrict__ bm, u32* __restrict__ kmax, u64* __restrict__ nn) {
    const int side = blockIdx.y;
    const float* full = side ? fs : fr;
    const float* corr = side ? cs : cr;
    const int ib = blockIdx.x & 3, ch = blockIdx.x >> 2;
    const int t = threadIdx.x;

    // folded k_bm: 235*256 = 60160 >= 60000 entries (side-0 blocks 0..234)
    int gb = side * 1024 + blockIdx.x;
    if (gb < 235) {
        int e = gb * 256 + t;
        if (e < 2 * NBACK) {
            int s2 = e < NBACK ? 0 : 1;
            int v = s2 ? sbi[e - NBACK] : rbi[e];
            atomicOr(&bm[s2 * BM_WORDS_I + (v >> 5)], 1u << (v & 31));
        }
    } else if (gb >= 1024 && gb < 1040) {
        // folded kmax insert: 16 side-1 blocks x 256 = 4096 entries
        int e = (gb - 1024) * 256 + t;
        int xi = gti[2*e], yi = gti[2*e+1];
        atomicMax(&kmax[xi * 2048 + yi], (u32)e + 1u);   // last-wins = max k
    }

    __shared__ float4 sx4[49], sy4[49], sz4[49], sw4[49];
    const int j0 = ch * NN_CHUNK;
    if (t < 49) {
        int b4 = j0 + t * 4;
        float xx[4], yy[4], zz[4], ww[4];
        #pragma unroll
        for (int u = 0; u < 4; ++u) {
            int j = b4 + u;
            if (j < NFULL) {
                float x = full[j*3], y = full[j*3+1], z = full[j*3+2];
                xx[u] = x; yy[u] = y; zz[u] = z;
                ww[u] = fmaf(x, x, fmaf(y, y, z*z));
            } else {
                xx[u] = 0.f; yy[u] = 0.f; zz[u] = 0.f; ww[u] = 3.0e38f;  // sentinel
            }
        }
        sx4[t] = make_float4(xx[0], xx[1], xx[2], xx[3]);
        sy4[t] = make_float4(yy[0], yy[1], yy[2], yy[3]);
        sz4[t] = make_float4(zz[0], zz[1], zz[2], zz[3]);
        sw4[t] = make_float4(ww[0], ww[1], ww[2], ww[3]);
    }

    float ax[2], ay[2], az[2], bd[2];
    int bg[2];
    #pragma unroll
    for (int q = 0; q < 2; ++q) {
        int i = ib * 512 + q * 256 + t;
        float cx = corr[i*3], cy = corr[i*3+1], cz = corr[i*3+2];
        ax[q] = -2.f*cx; ay[q] = -2.f*cy; az[q] = -2.f*cz;
        bd[q] = 3.4e38f; bg[q] = 0;
    }
    __syncthreads();

    #pragma unroll 2
    for (int g = 0; g < 49; ++g) {
        float4 X = sx4[g], Y = sy4[g], Z = sz4[g], W = sw4[g];
        f32x2 xlo = {X.x, X.y}, xhi = {X.z, X.w};
        f32x2 ylo = {Y.x, Y.y}, yhi = {Y.z, Y.w};
        f32x2 zlo = {Z.x, Z.y}, zhi = {Z.z, Z.w};
        f32x2 wlo = {W.x, W.y}, whi = {W.z, W.w};
        #pragma unroll
        for (int q = 0; q < 2; ++q) {
            f32x2 aq = {ax[q], ax[q]}, bq = {ay[q], ay[q]}, cq2 = {az[q], az[q]};
            f32x2 dlo = __builtin_elementwise_fma(aq, xlo,
                          __builtin_elementwise_fma(bq, ylo,
                            __builtin_elementwise_fma(cq2, zlo, wlo)));
            f32x2 dhi = __builtin_elementwise_fma(aq, xhi,
                          __builtin_elementwise_fma(bq, yhi,
                            __builtin_elementwise_fma(cq2, zhi, whi)));
            f32x2 m2 = __builtin_elementwise_min(dlo, dhi);
            float gm = fminf(m2.x, m2.y);
            bool win = gm < bd[q];
            bd[q] = fminf(bd[q], gm);
            bg[q] = win ? g : bg[q];
        }
    }

    #pragma unroll
    for (int q = 0; q < 2; ++q) {
        int gsel = bg[q];
        float4 X = sx4[gsel], Y = sy4[gsel], Z = sz4[gsel], W = sw4[gsel];
        f32x2 xlo = {X.x, X.y}, xhi = {X.z, X.w};
        f32x2 ylo = {Y.x, Y.y}, yhi = {Y.z, Y.w};
        f32x2 zlo = {Z.x, Z.y}, zhi = {Z.z, Z.w};
        f32x2 wlo = {W.x, W.y}, whi = {W.z, W.w};
        f32x2 aq = {ax[q], ax[q]}, bq = {ay[q], ay[q]}, cq2 = {az[q], az[q]};
        f32x2 dlo = __builtin_elementwise_fma(aq, xlo,
                      __builtin_elementwise_fma(bq, ylo,
                        __builtin_elementwise_fma(cq2, zlo, wlo)));
        f32x2 dhi = __builtin_elementwise_fma(aq, xhi,
                      __builtin_elementwise_fma(bq, yhi,
                        __builtin_elementwise_fma(cq2, zhi, whi)));
        float dv[4] = {dlo.x, dlo.y, dhi.x, dhi.y};
        u32 bj = (u32)(j0 + gsel * 4);
        bool found = false;
        #pragma unroll
        for (int u = 0; u < 4; ++u) {
            if (!found && dv[u] == bd[q]) { bj = (u32)(j0 + gsel*4 + u); found = true; }
        }
        int i = ib * 512 + q * 256 + t;
        float cn = 0.25f * fmaf(ax[q], ax[q], fmaf(ay[q], ay[q], az[q]*az[q]));
        float bf = bd[q] + cn;
        u32 db = __float_as_uint(bf);
        db = (db & 0x80000000u) ? ~db : (db | 0x80000000u);
        atomicMin(&nn[side * 2048 + i], ((u64)db << 32) | bj);
    }
}

// ---------------- msc: loss2 + gtb-set + winner-check/cand emit (no barriers) ------
// 16 blocks x 256, one entry per thread. kmax inserts completed in k_nn (two
// kernel boundaries upstream provide ordering).
__global__ __launch_bounds__(256) void k_msc(
        const u64* __restrict__ nn, const u32* __restrict__ bm,
        const float* __restrict__ spm, const int* __restrict__ gti,
        const float* __restrict__ gtv,
        u32* __restrict__ gtb, const u32* __restrict__ kmax,
        u64* __restrict__ cand, u32* __restrict__ cnt, float* __restrict__ acc) {
    const int b = blockIdx.x, t = threadIdx.x;
    const int e = b * 256 + t;   // 0..4095
    __shared__ float red2[4];

    float c = fabsf((1.f - spm[e]) - (float)mask_of(nn, bm, e, e >> 11));
    int xi = gti[2*e], yi = gti[2*e+1];
    u32 cell = (u32)(xi * 2048 + yi);
    u32 masked = mask_of(nn, bm, xi, 0) & mask_of(nn, bm, 2048 + yi, 1);
    if (masked) {
        atomicOr(&gtb[xi * 64 + (yi >> 5)], 1u << (yi & 31));
        if (kmax[cell] == (u32)e + 1u) {        // last-wins winner
            u32 vb = __float_as_uint(gtv[e]);   // overlaps >= 0 -> bits monotonic
            u32 idx = atomicAdd(&cnt[0], 1u);
            cand[idx] = ((u64)vb << 22) | (u32)(0x3FFFFF - cell);
        }
    }

    for (int o = 32; o; o >>= 1) c += __shfl_xor(c, o);
    if ((t & 63) == 0) red2[t >> 6] = c;
    __syncthreads();
    if (t == 0) atomicAdd(&acc[2], red2[0] + red2[1] + red2[2] + red2[3]);
}

// ---------------- top-256 cap, spread over 16 blocks ----------------
__global__ __launch_bounds__(256) void k_top(const u64* __restrict__ cand,
                                             const u32* __restrict__ cnt,
                                             u32* __restrict__ gtb) {
    const int n = (int)cnt[0];
    if (n <= MAXPTS) return;
    if (blockIdx.x * 256 >= n) return;
    __shared__ u64 keys[4096];
    const int t = threadIdx.x;
    for (int e = t; e < n; e += 256) keys[e] = cand[e];
    __syncthreads();
    int c = blockIdx.x * 256 + t;
    if (c >= n) return;
    u64 me = keys[c];
    int rank = 0;
    #pragma unroll 4
    for (int j = 0; j < n; ++j) rank += (keys[j] > me);
    if (rank >= MAXPTS) {
        u32 cell = 0x3FFFFFu - (u32)(me & 0x3FFFFFull);
        int row = cell >> 11, col = cell & 2047;
        atomicAnd(&gtb[row * 64 + (col >> 5)], ~(1u << (col & 31)));
    }
}

// ---------------- fused MFMA bf16 GEMM + laplace + row/col LSE partials (R13) ------
__global__ __launch_bounds__(256) void k_gemm(
        const float* __restrict__ A, const float* __restrict__ B,
        const float* __restrict__ spm, const u32* __restrict__ gtb,
        float4* __restrict__ rowp, float4* __restrict__ colp) {
    __shared__ __align__(16) short As[16384];   // 32 KB
    __shared__ __align__(16) short Bs[8192];    // 16 KB
    __shared__ u32 gtw[256];                    // 1 KB
    const int t = threadIdx.x;
    const int l = t & 63, wid = t >> 6;
    const int wm = wid >> 1, wn = wid & 1;
    const int i0 = blockIdx.y * 128, j0 = blockIdx.x * 64;

    gtw[t] = gtb[(size_t)(i0 + (t >> 1)) * 64 + (j0 >> 5) + (t & 1)];

    f32x4 acc[4][2] = {};

    for (int ks = 0; ks < 2; ++ks) {
        __syncthreads();
        #pragma unroll
        for (int it = 0; it < 12; ++it) {
            int sl = it * 256 + t;                 // 0..3071 slots of 16B
            int c = sl & 63, q = c >> 4, r15 = c & 15;
            const float* src;
            short* dst;
            int kf;
            if (it < 8) {                          // A: slots 0..2047
                int frag = sl >> 6;                // mf(8) x kf(4)
                kf = frag & 3;
                int row = (frag >> 2) * 16 + r15;
                src = A + (size_t)(i0 + row) * 256;
                dst = &As[sl * 8];
            } else {                               // B: slots 2048..3071
                int sl2 = sl - 2048;
                int frag = sl2 >> 6;               // nf(4) x kf(4)
                kf = frag & 3;
                int row = (frag >> 2) * 16 + r15;
                src = B + (size_t)(j0 + row) * 256;
                dst = &Bs[sl2 * 8];
            }
            int col = ks * 128 + kf * 32 + q * 8;
            float4 v0 = *(const float4*)(src + col);
            float4 v1 = *(const float4*)(src + col + 4);
            u32 w0 = __builtin_amdgcn_perm(__float_as_uint(v0.y), __float_as_uint(v0.x), 0x07060302u);
            u32 w1 = __builtin_amdgcn_perm(__float_as_uint(v0.w), __float_as_uint(v0.z), 0x07060302u);
            u32 w2 = __builtin_amdgcn_perm(__float_as_uint(v1.y), __float_as_uint(v1.x), 0x07060302u);
            u32 w3 = __builtin_amdgcn_perm(__float_as_uint(v1.w), __float_as_uint(v1.z), 0x07060302u);
            *(uint4*)dst = make_uint4(w0, w1, w2, w3);
        }
        __syncthreads();

        #pragma unroll
        for (int kf = 0; kf < 4; ++kf) {
            short8 a[4], b[2];
            #pragma unroll
            for (int mi = 0; mi < 4; ++mi)
                a[mi] = *(const short8*)&As[(((wm*4 + mi)*4 + kf) << 9) + l*8];
            #pragma unroll
            for (int ni = 0; ni < 2; ++ni)
                b[ni] = *(const short8*)&Bs[(((wn*2 + ni)*4 + kf) << 9) + l*8];
            #pragma unroll
            for (int mi = 0; mi < 4; ++mi)
                #pragma unroll
                for (int ni = 0; ni < 2; ++ni)
                    acc[mi][ni] = __builtin_amdgcn_mfma_f32_16x16x32_bf16(
                        a[mi], b[ni], acc[mi][ni], 0, 0, 0);
        }
    }

    // epilogue: C/D layout col=lane&15, row=(lane>>4)*4+reg [m89-verified]
    const int cq = l >> 4, cr = l & 15;
    const int rows0 = i0 + wm * 64, cols0 = j0 + wn * 32;

    float vmj[2];
    #pragma unroll
    for (int ni = 0; ni < 2; ++ni) vmj[ni] = 1.f - spm[2048 + cols0 + ni*16 + cr];
    float vmi[4][4];
    #pragma unroll
    for (int mi = 0; mi < 4; ++mi)
        #pragma unroll
        for (int rr = 0; rr < 4; ++rr)
            vmi[mi][rr] = 1.f - spm[rows0 + mi*16 + cq*4 + rr];

    u32 gmask = 0;
    #pragma unroll
    for (int mi = 0; mi < 4; ++mi)
        #pragma unroll
        for (int rr = 0; rr < 4; ++rr) {
            u32 w = gtw[(wm*64 + mi*16 + cq*4 + rr) * 2 + wn];
            #pragma unroll
            for (int ni = 0; ni < 2; ++ni)
                if ((w >> (ni*16 + cr)) & 1u) gmask |= 1u << (mi*8 + ni*4 + rr);
        }
    #pragma unroll
    for (int mi = 0; mi < 4; ++mi)
        #pragma unroll
        for (int ni = 0; ni < 2; ++ni)
            #pragma unroll
            for (int rr = 0; rr < 4; ++rr) {
                float s  = acc[mi][ni][rr];
                float fs = fmaxf(2.f - 2.f*s, 0.f);
                acc[mi][ni][rr] = sqrtf(fs) * expf(0.5f * vmi[mi][rr] * vmj[ni]);
            }

    const int jt2 = blockIdx.x * 2 + wn;   // 0..63
    const int it2 = blockIdx.y * 2 + wm;   // 0..31

    #pragma unroll
    for (int mi = 0; mi < 4; ++mi)
        #pragma unroll
        for (int rr = 0; rr < 4; ++rr) {
            float lp0, ln0, lp1, ln1;
            circle_terms(acc[mi][0][rr], (gmask >> (mi*8 + rr)) & 1, lp0, ln0);
            circle_terms(acc[mi][1][rr], (gmask >> (mi*8 + 4 + rr)) & 1, lp1, ln1);
            float mp = fmaxf(lp0, lp1), mn = fmaxf(ln0, ln1);
            #pragma unroll
            for (int o = 1; o < 16; o <<= 1) {
                mp = fmaxf(mp, __shfl_xor(mp, o));
                mn = fmaxf(mn, __shfl_xor(mn, o));
            }
            float sp = expf(lp0 - mp) + expf(lp1 - mp);
            float sn = expf(ln0 - mn) + expf(ln1 - mn);
            #pragma unroll
            for (int o = 1; o < 16; o <<= 1) {
                sp += __shfl_xor(sp, o);
                sn += __shfl_xor(sn, o);
            }
            if (cr == mi*4 + rr) {
                int row = rows0 + mi*16 + cq*4 + rr;
                rowp[(size_t)jt2 * 2048 + row] = make_float4(mp, sp, mn, sn);
            }
        }

    #pragma unroll
    for (int ni = 0; ni < 2; ++ni) {
        float lp[16], ln[16];
        #pragma unroll
        for (int mi = 0; mi < 4; ++mi)
            #pragma unroll
            for (int rr = 0; rr < 4; ++rr)
                circle_terms(acc[mi][ni][rr], (gmask >> (mi*8 + ni*4 + rr)) & 1,
                             lp[mi*4+rr], ln[mi*4+rr]);
        float mp = lp[0], mn = ln[0];
        #pragma unroll
        for (int e = 1; e < 16; ++e) { mp = fmaxf(mp, lp[e]); mn = fmaxf(mn, ln[e]); }
        #pragma unroll
        for (int o = 16; o < 64; o <<= 1) {
            mp = fmaxf(mp, __shfl_xor(mp, o));
            mn = fmaxf(mn, __shfl_xor(mn, o));
        }
        float sp = 0.f, sn = 0.f;
        #pragma unroll
        for (int e = 0; e < 16; ++e) { sp += expf(lp[e] - mp); sn += expf(ln[e] - mn); }
        #pragma unroll
        for (int o = 16; o < 64; o <<= 1) {
            sp += __shfl_xor(sp, o);
            sn += __shfl_xor(sn, o);
        }
        if (cq == 0) {
            int col = cols0 + ni*16 + cr;
            colp[(size_t)it2 * 2048 + col] = make_float4(mp, sp, mn, sn);
        }
    }
}

// ---------------- merge partials: 64 blocks, 4 threads/element (R18, proven) ------
__global__ __launch_bounds__(256) void k_merge(const float4* __restrict__ rowp,
                                               const float4* __restrict__ colp,
                                               float* __restrict__ acc,
                                               u32* __restrict__ cnt,
                                               float* __restrict__ out) {
    const int t = threadIdx.x;
    const int b = blockIdx.x;    // 0..63
    const int sub = t & 3;
    float Mp = -1e30f, Sp = 0.f, Mn = -1e30f, Sn = 0.f;

    if (b < 32) {
        int row = (b * 256 + t) >> 2;           // 0..2047
        int base = sub * 16;
        #pragma unroll
        for (int j = 0; j < 16; j += 8) {
            float4 pb[8];
            #pragma unroll
            for (int u = 0; u < 8; ++u)
                pb[u] = rowp[(size_t)(base + j + u) * 2048 + row];
            #pragma unroll
            for (int u = 0; u < 8; ++u) {
                lse_merge(Mp, Sp, pb[u].x, pb[u].y);
                lse_merge(Mn, Sn, pb[u].z, pb[u].w);
            }
        }
    } else {
        int col = ((b - 32) * 256 + t) >> 2;    // 0..2047
        int base = sub * 8;
        float4 pb[8];
        #pragma unroll
        for (int u = 0; u < 8; ++u)
            pb[u] = colp[(size_t)(base + u) * 2048 + col];
        #pragma unroll
        for (int u = 0; u < 8; ++u) {
            lse_merge(Mp, Sp, pb[u].x, pb[u].y);
            lse_merge(Mn, Sn, pb[u].z, pb[u].w);
        }
    }

    #pragma unroll
    for (int o = 1; o < 4; o <<= 1) {
        float M2 = __shfl_xor(Mp, o), S2 = __shfl_xor(Sp, o);
        lse_merge(Mp, Sp, M2, S2);
        M2 = __shfl_xor(Mn, o); S2 = __shfl_xor(Sn, o);
        lse_merge(Mn, Sn, M2, S2);
    }

    float lv = 0.f;
    if (sub == 0) {
        float x = (Mp + logf(Sp)) + (Mn + logf(Sn));
        lv = softplus_(x) * (1.f / 24.f);
    }
    for (int o = 32; o; o >>= 1) lv += __shfl_xor(lv, o);
    __shared__ float wsum[4];
    __shared__ u32 tic;
    if ((t & 63) == 0) wsum[t >> 6] = lv;
    __syncthreads();
    if (t == 0) {
        atomicAdd(&acc[b < 32 ? 0 : 1], wsum[0] + wsum[1] + wsum[2] + wsum[3]);
        __threadfence();
        tic = atomicAdd(&cnt[1], 1u);
    }
    __syncthreads();
    if (t == 0 && tic == 63u) {
        __threadfence();
        float a0 = atomicAdd(&acc[0], 0.f);
        float a1 = atomicAdd(&acc[1], 0.f);
        float a2 = atomicAdd(&acc[2], 0.f);
        float l1 = (a0 + a1) * (0.5f / 2048.f);
        float l2 = a2 * (1.f / 4096.f);
        out[0] = l1 + l2; out[1] = l1; out[2] = l2;
    }
}

extern "C" void kernel_launch(void* const* d_in, const int* in_sizes, int n_in,
                              void* d_out, int out_size, void* d_ws, size_t ws_size,
                              hipStream_t stream) {
    (void)in_sizes; (void)n_in; (void)out_size; (void)ws_size;
    const float* ref_points = (const float*)d_in[0];
    const float* src_points = (const float*)d_in[1];
    const float* ref_c      = (const float*)d_in[2];
    const float* src_c      = (const float*)d_in[3];
    const float* ref_f      = (const float*)d_in[4];
    const float* src_f      = (const float*)d_in[5];
    const int*   gti        = (const int*)d_in[6];
    const float* gtv        = (const float*)d_in[7];
    const float* spm        = (const float*)d_in[8];
    const int*   rbi        = (const int*)d_in[9];
    const int*   sbi        = (const int*)d_in[10];

    char* ws = (char*)d_ws;
    float4* rowp = (float4*)(ws + OFF_ROWP);
    float4* colp = (float4*)(ws + OFF_COLP);
    u32*   gtb  = (u32*)  (ws + OFF_GTB);
    u64*   nn   = (u64*)  (ws + OFF_NN);
    u64*   cand = (u64*)  (ws + OFF_CAND);
    float* acc  = (float*)(ws + OFF_ACC);
    u32*   cnt  = (u32*)  (ws + OFF_CNT);
    u32*   bm   = (u32*)  (ws + OFF_BM);
    u32*   kmax = (u32*)  (ws + OFF_KMAX);

    k_init <<<128, 256, 0, stream>>>((uint4*)gtb, nn, acc, cnt, bm, kmax, gti);
    k_nn   <<<dim3(1024, 2), 256, 0, stream>>>(ref_points, src_points, ref_c, src_c,
                                               rbi, sbi, gti, bm, kmax, nn);
    k_msc  <<<16, 256, 0, stream>>>(nn, bm, spm, gti, gtv, gtb, kmax, cand, cnt, acc);
    k_top  <<<16, 256, 0, stream>>>(cand, cnt, gtb);
    k_gemm <<<dim3(32, 16), 256, 0, stream>>>(ref_f, src_f, spm, gtb, rowp, colp);
    k_merge<<<64, 256, 0, stream>>>(rowp, colp, acc, cnt, (float*)d_out);
}